// Round 2
// baseline (452.589 us; speedup 1.0000x reference)
//
#include <hip/hip_runtime.h>

typedef unsigned short u16;
typedef __attribute__((ext_vector_type(8))) __bf16 bf16x8;
typedef __attribute__((ext_vector_type(4))) float f32x4;
typedef __attribute__((ext_vector_type(4))) float f4;
typedef __attribute__((ext_vector_type(8))) unsigned short u16x8;
typedef __attribute__((ext_vector_type(4))) unsigned short u16x4;

__device__ __forceinline__ u16 f2bf(float f) {
  union { float f; unsigned int u; } x; x.f = f;
  unsigned int r = x.u + 0x7FFFu + ((x.u >> 16) & 1u);
  return (u16)(r >> 16);
}
__device__ __forceinline__ float bf2f(u16 h) {
  union { unsigned int u; float f; } x; x.u = ((unsigned int)h) << 16;
  return x.f;
}

typedef const __attribute__((address_space(1))) void* gas_t;
typedef __attribute__((address_space(3))) void* las_t;
__device__ __forceinline__ void gload_lds16(const void* g, void* l) {
  __builtin_amdgcn_global_load_lds((gas_t)g, (las_t)l, 16, 0, 0);
}

// ---------------- cast X fp32 -> bf16 ----------------
__global__ __launch_bounds__(256) void k_castx(const float* __restrict__ X, u16* __restrict__ Xb) {
  int i = blockIdx.x * 256 + threadIdx.x;          // 8 floats per thread
  const f4* src = (const f4*)X + (size_t)i * 2;
  f4 a = src[0], b = src[1];
  u16x8 o;
#pragma unroll
  for (int j = 0; j < 4; ++j) { o[j] = f2bf(a[j]); o[4 + j] = f2bf(b[j]); }
  *((u16x8*)Xb + i) = o;
}

// ---------------- transpose+cast W [4096][12288] fp32 -> Wt [12288][4096] bf16 ----
__global__ __launch_bounds__(256) void k_wtrans(const float* __restrict__ W, u16* __restrict__ Wt) {
  const int N = 12288, K = 4096;
  int n0 = blockIdx.x * 64;
  int k0 = blockIdx.y * 64;
  int t = threadIdx.x;
  __shared__ float tile[64][65];
  int tr = t >> 4;           // 0..15
  int tc4 = (t & 15) * 4;    // 0..60
#pragma unroll
  for (int p = 0; p < 4; ++p) {
    int k = k0 + p * 16 + tr;
    f4 v = *(const f4*)&W[(size_t)k * N + n0 + tc4];
#pragma unroll
    for (int j = 0; j < 4; ++j) tile[p * 16 + tr][tc4 + j] = v[j];
  }
  __syncthreads();
#pragma unroll
  for (int p = 0; p < 4; ++p) {
    int n = n0 + p * 16 + tr;
    u16x4 o;
#pragma unroll
    for (int j = 0; j < 4; ++j) o[j] = f2bf(tile[tc4 + j][p * 16 + tr]);
    *(u16x4*)&Wt[(size_t)n * K + k0 + tc4] = o;
  }
}

// ---------------- GEMM: qkv[2048][12288] = Xb @ Wt^T + bias (bf16 out) ----------
// BM=128, BN=256, BK=32; 8 waves (2Mx4N), wave tile 64x64; 4-deep LDS pipeline,
// counted vmcnt (T4), LDS xor-swizzle (T2), setprio (T5), XCD swizzle (T1).
__global__ __launch_bounds__(512) void k_gemm2(const u16* __restrict__ A, const u16* __restrict__ Bt,
                                               const float* __restrict__ bias, u16* __restrict__ C) {
  const int K = 4096, N = 12288;
  int bid = blockIdx.x;                    // 768 blocks, 768 % 8 == 0
  int swz = (bid & 7) * 96 + (bid >> 3);   // XCD-aware remap (bijective)
  int bn = swz % 48, bm = swz / 48;
  const int t = threadIdx.x, w = t >> 6, lane = t & 63;
  const int lr = lane & 15, lg = lane >> 4;
  const int wm = w >> 2, wn = w & 3;
  __shared__ u16 lA[4 * 4096];             // [slab][128][32] bf16
  __shared__ u16 lB[4 * 8192];             // [slab][256][32] bf16
  f32x4 acc[4][4] = {};

  // staging: linear LDS dest, inverse-swizzled global source (rule #21)
  const int rA = t >> 2;                                    // 0..127
  const int csw = ((t & 3) * 8) ^ (((rA >> 1) & 3) << 3);   // swizzled col (elems)
  const u16* aSrc  = A  + (size_t)(bm * 128 + rA) * K + csw;
  const u16* bSrc0 = Bt + (size_t)(bn * 256 + rA) * K + csw;
  const u16* bSrc1 = bSrc0 + (size_t)128 * K;               // same swizzle: (row+128)>>1 & 3 unchanged
  u16* dstA  = &lA[w * 512];
  u16* dstB0 = &lB[w * 512];
  u16* dstB1 = &lB[4096 + w * 512];

  // fragment read offsets (swizzled): elem = row*32 + lg*8, ^ ((row>>1)&3)<<3
  int eA[4], eB[4];
  {
    int sw = ((lr >> 1) & 3) << 3;   // row>>1 & 3 depends only on lr here
#pragma unroll
    for (int i = 0; i < 4; ++i) {
      int rowA = wm * 64 + i * 16 + lr;
      eA[i] = (rowA * 32 + lg * 8) ^ sw;
      int rowB = wn * 64 + i * 16 + lr;
      eB[i] = (rowB * 32 + lg * 8) ^ sw;
    }
  }

  // prologue: stage tiles 0,1,2 (slabs 0,1,2); drain tile 0 only
#pragma unroll
  for (int p = 0; p < 3; ++p) {
    gload_lds16(aSrc  + p * 32, dstA  + p * 4096);
    gload_lds16(bSrc0 + p * 32, dstB0 + p * 8192);
    gload_lds16(bSrc1 + p * 32, dstB1 + p * 8192);
  }
  asm volatile("s_waitcnt vmcnt(6)" ::: "memory");
  __builtin_amdgcn_s_barrier();

  for (int u = 0; u < 128; ++u) {
    const int sA = (u & 3) * 4096, sB = (u & 3) * 8192;
    bf16x8 af[4], bfr[4];
#pragma unroll
    for (int i = 0; i < 4; ++i) af[i] = *(const bf16x8*)&lA[sA + eA[i]];
#pragma unroll
    for (int j = 0; j < 4; ++j) bfr[j] = *(const bf16x8*)&lB[sB + eB[j]];
    if (u < 125) {  // stage tile u+3 into slab (u+3)&3 (last read at block u-1, pre-barrier)
      const int s2A = ((u + 3) & 3) * 4096, s2B = ((u + 3) & 3) * 8192;
      gload_lds16(aSrc  + (u + 3) * 32, dstA  + s2A);
      gload_lds16(bSrc0 + (u + 3) * 32, dstB0 + s2B);
      gload_lds16(bSrc1 + (u + 3) * 32, dstB1 + s2B);
    }
    asm volatile("s_waitcnt lgkmcnt(0)" ::: "memory");
    __builtin_amdgcn_sched_barrier(0);
    __builtin_amdgcn_s_setprio(1);
#pragma unroll
    for (int i = 0; i < 4; ++i)
#pragma unroll
      for (int j = 0; j < 4; ++j)
        acc[i][j] = __builtin_amdgcn_mfma_f32_16x16x32_bf16(af[i], bfr[j], acc[i][j], 0, 0, 0);
    __builtin_amdgcn_s_setprio(0);
    // counted drain: guarantee tile u+1 resident before next block's reads
    if (u < 125)       { asm volatile("s_waitcnt vmcnt(6)" ::: "memory"); }
    else if (u == 125) { asm volatile("s_waitcnt vmcnt(3)" ::: "memory"); }
    else if (u == 126) { asm volatile("s_waitcnt vmcnt(0)" ::: "memory"); }
    __builtin_amdgcn_s_barrier();
  }

  const int row0b = bm * 128 + wm * 64;
  const int col0b = bn * 256 + wn * 64;
#pragma unroll
  for (int i = 0; i < 4; ++i) {
    int row0 = row0b + i * 16 + lg * 4;
#pragma unroll
    for (int j = 0; j < 4; ++j) {
      int col = col0b + j * 16 + lr;
      float bv = bias[col];
#pragma unroll
      for (int r = 0; r < 4; ++r)
        C[(size_t)(row0 + r) * N + col] = f2bf(acc[i][j][r] + bv);
    }
  }
}

// ---------------- RoPE + split/reshape: qkv bf16 -> Q (scaled), K, Vt ----------
__global__ __launch_bounds__(256) void k_rope(const u16* __restrict__ qkv,
                                              u16* __restrict__ Qo, u16* __restrict__ Ko,
                                              u16* __restrict__ Vto) {
  int bid = blockIdx.x;
  int sc = bid & 7, h = (bid >> 3) & 31, b = bid >> 8;
  int t = threadIdx.x;
  int sl = t >> 2, c = t & 3;
  int s = sc * 64 + sl;
  __shared__ u16 vt[128][88];
  const u16* base = qkv + (size_t)(b * 512 + s) * 12288 + h * 384;
  int dbase = c * 32, pbase = dbase ^ 64;
  int j0 = dbase & 63;
  float sgn = (c < 2) ? -1.f : 1.f;
  size_t qkbase = ((size_t)(b * 32 + h) * 512 + s) * 128;
#pragma unroll
  for (int g = 0; g < 4; ++g) {
    u16x8 q1 = *(const u16x8*)(base + dbase + g * 8);
    u16x8 q2 = *(const u16x8*)(base + pbase + g * 8);
    u16x8 k1 = *(const u16x8*)(base + 128 + dbase + g * 8);
    u16x8 k2 = *(const u16x8*)(base + 128 + pbase + g * 8);
    u16x8 vv = *(const u16x8*)(base + 256 + dbase + g * 8);
    u16x8 oq, ok;
#pragma unroll
    for (int i = 0; i < 8; ++i) {
      float j = (float)(j0 + g * 8 + i);
      float ang = (float)s * __expf(j * -0.14391156831f);  // ln(10000)/64
      float sv, cv; __sincosf(ang, &sv, &cv);
      oq[i] = f2bf((bf2f(q1[i]) * cv + sgn * bf2f(q2[i]) * sv) * 0.08838834765f);
      ok[i] = f2bf(bf2f(k1[i]) * cv + sgn * bf2f(k2[i]) * sv);
      vt[dbase + g * 8 + i][sl] = vv[i];
    }
    *(u16x8*)(Qo + qkbase + dbase + g * 8) = oq;
    *(u16x8*)(Ko + qkbase + dbase + g * 8) = ok;
  }
  __syncthreads();
  int d = t & 127, s2 = (t >> 7) * 32;
  size_t vb = ((size_t)(b * 32 + h) * 128 + d) * 512 + sc * 64 + s2;
#pragma unroll
  for (int g = 0; g < 4; ++g)
    *(u16x8*)(Vto + vb + g * 8) = *(const u16x8*)&vt[d][s2 + g * 8];
}

// ---------------- causal flash attention ----------------
__global__ __launch_bounds__(256) void k_attn(const u16* __restrict__ Q, const u16* __restrict__ Kg,
                                              const u16* __restrict__ Vt, float* __restrict__ Out) {
  int bid = blockIdx.x;
  int qb = bid & 3, h = (bid >> 2) & 31, b = bid >> 7;
  int t = threadIdx.x, w = t >> 6, lane = t & 63;
  int lr = lane & 15, lg = lane >> 4;
  size_t bh = (size_t)b * 32 + h;
  const u16* Qp = Q + (bh * 512 + qb * 128) * 128;
  const u16* Kp = Kg + bh * 512 * 128;
  const u16* Vp = Vt + bh * 128 * 512;
  __shared__ u16 lK[64][136];
  __shared__ u16 lV[128][88];
  __shared__ u16 lP[4][16][88];
  bf16x8 qf[2][4];
#pragma unroll
  for (int mt = 0; mt < 2; ++mt)
#pragma unroll
    for (int dc = 0; dc < 4; ++dc)
      qf[mt][dc] = *(const bf16x8*)(Qp + (size_t)(w * 32 + mt * 16 + lr) * 128 + dc * 32 + lg * 8);
  f32x4 o[2][8] = {};
  float mrow[2][4], lrow[2][4];
#pragma unroll
  for (int mt = 0; mt < 2; ++mt)
#pragma unroll
    for (int r = 0; r < 4; ++r) { mrow[mt][r] = -1e30f; lrow[mt][r] = 0.f; }
  int q0 = qb * 128;
  for (int kv0 = 0; kv0 < q0 + 128; kv0 += 64) {
    __syncthreads();
#pragma unroll
    for (int p = 0; p < 4; ++p) {
      int idx = t + p * 256;
      int r = idx >> 4, cc = (idx & 15) * 8;
      *(bf16x8*)&lK[r][cc] = *(const bf16x8*)(Kp + (size_t)(kv0 + r) * 128 + cc);
    }
#pragma unroll
    for (int p = 0; p < 4; ++p) {
      int idx = t + p * 256;
      int r = idx >> 3, cc = (idx & 7) * 8;
      *(bf16x8*)&lV[r][cc] = *(const bf16x8*)(Vp + (size_t)r * 512 + kv0 + cc);
    }
    __syncthreads();
    bool diag = (kv0 >= q0);
#pragma unroll
    for (int mt = 0; mt < 2; ++mt) {
      f32x4 sacc[4] = {};
#pragma unroll
      for (int nt = 0; nt < 4; ++nt)
#pragma unroll
        for (int dc = 0; dc < 4; ++dc) {
          bf16x8 kf = *(const bf16x8*)&lK[nt * 16 + lr][dc * 32 + lg * 8];
          sacc[nt] = __builtin_amdgcn_mfma_f32_16x16x32_bf16(qf[mt][dc], kf, sacc[nt], 0, 0, 0);
        }
      int rbase = q0 + w * 32 + mt * 16 + lg * 4;
      if (diag) {
#pragma unroll
        for (int nt = 0; nt < 4; ++nt)
#pragma unroll
          for (int r = 0; r < 4; ++r)
            if (kv0 + nt * 16 + lr > rbase + r) sacc[nt][r] = -1e30f;
      }
#pragma unroll
      for (int r = 0; r < 4; ++r) {
        float mx = fmaxf(fmaxf(sacc[0][r], sacc[1][r]), fmaxf(sacc[2][r], sacc[3][r]));
#pragma unroll
        for (int off = 8; off; off >>= 1) mx = fmaxf(mx, __shfl_xor(mx, off));
        float mold = mrow[mt][r];
        float mnew = fmaxf(mold, mx);
        float alpha = __expf(mold - mnew);
        float ps = 0.f;
#pragma unroll
        for (int nt = 0; nt < 4; ++nt) { float p = __expf(sacc[nt][r] - mnew); sacc[nt][r] = p; ps += p; }
#pragma unroll
        for (int off = 8; off; off >>= 1) ps += __shfl_xor(ps, off);
        mrow[mt][r] = mnew;
        lrow[mt][r] = lrow[mt][r] * alpha + ps;
#pragma unroll
        for (int dt = 0; dt < 8; ++dt) o[mt][dt][r] *= alpha;
      }
#pragma unroll
      for (int nt = 0; nt < 4; ++nt)
#pragma unroll
        for (int r = 0; r < 4; ++r)
          lP[w][lg * 4 + r][nt * 16 + lr] = f2bf(sacc[nt][r]);
#pragma unroll
      for (int kc = 0; kc < 2; ++kc) {
        bf16x8 pf = *(const bf16x8*)&lP[w][lr][kc * 32 + lg * 8];
#pragma unroll
        for (int dt = 0; dt < 8; ++dt) {
          bf16x8 vf = *(const bf16x8*)&lV[dt * 16 + lr][kc * 32 + lg * 8];
          o[mt][dt] = __builtin_amdgcn_mfma_f32_16x16x32_bf16(pf, vf, o[mt][dt], 0, 0, 0);
        }
      }
    }
  }
#pragma unroll
  for (int mt = 0; mt < 2; ++mt)
#pragma unroll
    for (int r = 0; r < 4; ++r) {
      float inv = 1.f / lrow[mt][r];
      int rowg = q0 + w * 32 + mt * 16 + lg * 4 + r;
      size_t ob = ((size_t)b * 512 + rowg) * 4096 + (size_t)h * 128;
#pragma unroll
      for (int dt = 0; dt < 8; ++dt)
        Out[ob + dt * 16 + lr] = o[mt][dt][r] * inv;
    }
}

extern "C" void kernel_launch(void* const* d_in, const int* in_sizes, int n_in,
                              void* d_out, int out_size, void* d_ws, size_t ws_size,
                              hipStream_t stream) {
  const float* X = (const float*)d_in[0];     // [4,512,4096]
  const float* W = (const float*)d_in[1];     // [4096,12288]
  const float* bias = (const float*)d_in[2];  // [12288]
  float* out = (float*)d_out;
  char* ws = (char*)d_ws;
  u16* Xb  = (u16*)(ws);
  u16* Wt  = (u16*)(ws + 16777216);
  u16* qkv = (u16*)(ws + 117440512);
  u16* Qb  = (u16*)(ws);
  u16* Kb  = (u16*)(ws + 16777216);
  u16* Vtb = (u16*)(ws + 33554432);

  k_castx<<<4096, 256, 0, stream>>>(X, Xb);
  k_wtrans<<<dim3(192, 64), 256, 0, stream>>>(W, Wt);
  k_gemm2<<<768, 512, 0, stream>>>(Xb, Wt, bias, qkv);
  k_rope<<<1024, 256, 0, stream>>>(qkv, Qb, Kb, Vtb);
  k_attn<<<512, 256, 0, stream>>>(Qb, Kb, Vtb, out);
}

// Round 3
// 351.074 us; speedup vs baseline: 1.2892x; 1.2892x over previous
//
#include <hip/hip_runtime.h>

typedef unsigned short u16;
typedef __attribute__((ext_vector_type(8))) __bf16 bf16x8;
typedef __attribute__((ext_vector_type(4))) float f32x4;
typedef __attribute__((ext_vector_type(4))) float f4;
typedef __attribute__((ext_vector_type(8))) unsigned short u16x8;
typedef __attribute__((ext_vector_type(4))) unsigned short u16x4;

__device__ __forceinline__ u16 f2bf(float f) {
  union { float f; unsigned int u; } x; x.f = f;
  unsigned int r = x.u + 0x7FFFu + ((x.u >> 16) & 1u);
  return (u16)(r >> 16);
}
__device__ __forceinline__ float bf2f(u16 h) {
  union { unsigned int u; float f; } x; x.u = ((unsigned int)h) << 16;
  return x.f;
}

typedef const __attribute__((address_space(1))) void* gas_t;
typedef __attribute__((address_space(3))) void* las_t;
__device__ __forceinline__ void gload_lds16(const void* g, void* l) {
  __builtin_amdgcn_global_load_lds((gas_t)g, (las_t)l, 16, 0, 0);
}

#define WAITL0 do { asm volatile("s_waitcnt lgkmcnt(0)" ::: "memory"); \
                    __builtin_amdgcn_sched_barrier(0); } while (0)

// ---------------- cast X fp32 -> bf16 ----------------
__global__ __launch_bounds__(256) void k_castx(const float* __restrict__ X, u16* __restrict__ Xb) {
  int i = blockIdx.x * 256 + threadIdx.x;          // 8 floats per thread
  const f4* src = (const f4*)X + (size_t)i * 2;
  f4 a = src[0], b = src[1];
  u16x8 o;
#pragma unroll
  for (int j = 0; j < 4; ++j) { o[j] = f2bf(a[j]); o[4 + j] = f2bf(b[j]); }
  *((u16x8*)Xb + i) = o;
}

// ---------------- transpose+cast W [4096][12288] fp32 -> Wt [12288][4096] bf16 ----
__global__ __launch_bounds__(256) void k_wtrans(const float* __restrict__ W, u16* __restrict__ Wt) {
  const int N = 12288, K = 4096;
  int n0 = blockIdx.x * 64;
  int k0 = blockIdx.y * 64;
  int t = threadIdx.x;
  __shared__ float tile[64][65];
  int tr = t >> 4;           // 0..15
  int tc4 = (t & 15) * 4;    // 0..60
#pragma unroll
  for (int p = 0; p < 4; ++p) {
    int k = k0 + p * 16 + tr;
    f4 v = *(const f4*)&W[(size_t)k * N + n0 + tc4];
#pragma unroll
    for (int j = 0; j < 4; ++j) tile[p * 16 + tr][tc4 + j] = v[j];
  }
  __syncthreads();
#pragma unroll
  for (int p = 0; p < 4; ++p) {
    int n = n0 + p * 16 + tr;
    u16x4 o;
#pragma unroll
    for (int j = 0; j < 4; ++j) o[j] = f2bf(tile[tc4 + j][p * 16 + tr]);
    *(u16x4*)&Wt[(size_t)n * K + k0 + tc4] = o;
  }
}

// ---------------- GEMM: qkv[2048][12288] = Xb @ Wt^T + bias (bf16 out) ----------
// BM=128, BN=256, BK=64; 8 waves (2Mx4N), wave tile 64x64; 3-slab LDS pipeline,
// 4 phases/K-tile with ds_read||gload||MFMA interleave, counted vmcnt(6),
// barrier AFTER vmcnt (collective stage-complete), T2 chunk^row swizzle.
#define MFMA8(FA, FB, IB, JB)                                              \
  _Pragma("unroll")                                                        \
  for (int i2 = 0; i2 < 2; ++i2)                                           \
    _Pragma("unroll")                                                      \
    for (int j2 = 0; j2 < 2; ++j2)                                         \
      _Pragma("unroll")                                                    \
      for (int kk = 0; kk < 2; ++kk)                                       \
        acc[(IB) + i2][(JB) + j2] = __builtin_amdgcn_mfma_f32_16x16x32_bf16( \
            FA[i2][kk], FB[j2][kk], acc[(IB) + i2][(JB) + j2], 0, 0, 0);

#define TILE_BODY(U, STAGE, VMN, CROSS)                                     \
  {                                                                         \
    const int s_ = (U) % 3, sn_ = ((U) + 1) % 3, s2_ = ((U) + 2) % 3;       \
    const size_t kc_ = (size_t)((U) + 2) * 64;                              \
    /* ---- P0 ---- */                                                      \
    WAITL0;                                                                 \
    __builtin_amdgcn_s_setprio(1); MFMA8(fA0, fB0, 0, 0);                   \
    __builtin_amdgcn_s_setprio(0);                                          \
    if (STAGE) {                                                            \
      gload_lds16(aS + kc_,         &lds[s2_ * 24576 + (w * 16) * 64]);     \
      gload_lds16(aS + 8 * K + kc_, &lds[s2_ * 24576 + (w * 16 + 8) * 64]); \
    }                                                                       \
    _Pragma("unroll") for (int j2 = 0; j2 < 2; ++j2)                        \
      _Pragma("unroll") for (int kk = 0; kk < 2; ++kk)                      \
        fB1[j2][kk] = *(const bf16x8*)&lds[s_ * 24576 + bBase + (2 + j2) * 1024 + ch[kk]]; \
    /* ---- P1 ---- */                                                      \
    WAITL0;                                                                 \
    __builtin_amdgcn_s_setprio(1); MFMA8(fA0, fB1, 0, 2);                   \
    __builtin_amdgcn_s_setprio(0);                                          \
    if (STAGE) {                                                            \
      gload_lds16(bS + kc_,         &lds[s2_ * 24576 + 8192 + (w * 32) * 64]); \
      gload_lds16(bS + 8 * K + kc_, &lds[s2_ * 24576 + 8192 + (w * 32 + 8) * 64]); \
    }                                                                       \
    _Pragma("unroll") for (int i2 = 0; i2 < 2; ++i2)                        \
      _Pragma("unroll") for (int kk = 0; kk < 2; ++kk)                      \
        fA1[i2][kk] = *(const bf16x8*)&lds[s_ * 24576 + aBase + (2 + i2) * 1024 + ch[kk]]; \
    /* ---- P2 ---- */                                                      \
    WAITL0;                                                                 \
    __builtin_amdgcn_s_setprio(1); MFMA8(fA1, fB1, 2, 2);                   \
    __builtin_amdgcn_s_setprio(0);                                          \
    if (STAGE) {                                                            \
      gload_lds16(bS + 16 * K + kc_, &lds[s2_ * 24576 + 8192 + (w * 32 + 16) * 64]); \
      gload_lds16(bS + 24 * K + kc_, &lds[s2_ * 24576 + 8192 + (w * 32 + 24) * 64]); \
    }                                                                       \
    if ((VMN) == 6)      { asm volatile("s_waitcnt vmcnt(6)" ::: "memory"); } \
    else if ((VMN) == 0) { asm volatile("s_waitcnt vmcnt(0)" ::: "memory"); } \
    if (CROSS) {                                                            \
      __builtin_amdgcn_s_barrier();                                         \
      _Pragma("unroll") for (int i2 = 0; i2 < 2; ++i2)                      \
        _Pragma("unroll") for (int kk = 0; kk < 2; ++kk)                    \
          fA0[i2][kk] = *(const bf16x8*)&lds[sn_ * 24576 + aBase + i2 * 1024 + ch[kk]]; \
    }                                                                       \
    /* ---- P3 ---- */                                                      \
    __builtin_amdgcn_s_setprio(1); MFMA8(fA1, fB0, 2, 0);                   \
    __builtin_amdgcn_s_setprio(0);                                          \
    if (CROSS) {                                                            \
      _Pragma("unroll") for (int j2 = 0; j2 < 2; ++j2)                      \
        _Pragma("unroll") for (int kk = 0; kk < 2; ++kk)                    \
          fB0[j2][kk] = *(const bf16x8*)&lds[sn_ * 24576 + bBase + j2 * 1024 + ch[kk]]; \
    }                                                                       \
  }

__global__ __launch_bounds__(512) void k_gemm3(const u16* __restrict__ A, const u16* __restrict__ Bt,
                                               const float* __restrict__ bias, u16* __restrict__ C) {
  const int K = 4096, N = 12288;
  const int bn = blockIdx.x, bm = blockIdx.y;    // 48 x 16, bn-fast rasterization
  const int t = threadIdx.x, w = t >> 6, lane = t & 63;
  const int lr = lane & 15, lg = lane >> 4;
  const int wm = w >> 2, wn = w & 3;
  __shared__ u16 lds[3 * 24576];                 // slab: A[128][64] @0, B[256][64] @8192

  f32x4 acc[4][4] = {};
  bf16x8 fA0[2][2], fA1[2][2], fB0[2][2], fB1[2][2];   // [sub][kk]

  // staging source (pre-swizzled, rule #21): lane l covers row (l>>3), chunk (l&7)^(l>>3)
  const int r8 = lane >> 3;
  const int cgs = (lane & 7) ^ r8;
  const u16* aS = A  + (size_t)(bm * 128 + w * 16 + r8) * K + cgs * 8;
  const u16* bS = Bt + (size_t)(bn * 256 + w * 32 + r8) * K + cgs * 8;

  // fragment read offsets (swizzled): row&7 == lr&7 for all frags
  const int aBase = (wm * 64 + lr) * 64;
  const int bBase = 8192 + (wn * 64 + lr) * 64;
  const int ch[2] = { ((lg ^ (lr & 7)) * 8), (((4 + lg) ^ (lr & 7)) * 8) };

  // prologue: stage tiles 0,1 into slabs 0,1; drain tile 0 (collective); preload frags
#pragma unroll
  for (int tt = 0; tt < 2; ++tt) {
    gload_lds16(aS + tt * 64,         &lds[tt * 24576 + (w * 16) * 64]);
    gload_lds16(aS + 8 * K + tt * 64, &lds[tt * 24576 + (w * 16 + 8) * 64]);
#pragma unroll
    for (int p = 0; p < 4; ++p)
      gload_lds16(bS + p * 8 * K + tt * 64, &lds[tt * 24576 + 8192 + (w * 32 + p * 8) * 64]);
  }
  asm volatile("s_waitcnt vmcnt(6)" ::: "memory");
  __builtin_amdgcn_s_barrier();
#pragma unroll
  for (int i2 = 0; i2 < 2; ++i2)
#pragma unroll
    for (int kk = 0; kk < 2; ++kk) {
      fA0[i2][kk] = *(const bf16x8*)&lds[aBase + i2 * 1024 + ch[kk]];
      fB0[i2][kk] = *(const bf16x8*)&lds[bBase + i2 * 1024 + ch[kk]];
    }

  for (int u = 0; u < 62; ++u) TILE_BODY(u, true, 6, true);
  TILE_BODY(62, false, 0, true);
  TILE_BODY(63, false, -1, false);

  const int row0b = bm * 128 + wm * 64;
  const int col0b = bn * 256 + wn * 64;
#pragma unroll
  for (int i = 0; i < 4; ++i) {
    int row0 = row0b + i * 16 + lg * 4;
#pragma unroll
    for (int j = 0; j < 4; ++j) {
      int col = col0b + j * 16 + lr;
      float bv = bias[col];
#pragma unroll
      for (int r = 0; r < 4; ++r)
        C[(size_t)(row0 + r) * N + col] = f2bf(acc[i][j][r] + bv);
    }
  }
}

// ---------------- RoPE + split/reshape: qkv bf16 -> Q (scaled), K, Vt ----------
__global__ __launch_bounds__(256) void k_rope(const u16* __restrict__ qkv,
                                              u16* __restrict__ Qo, u16* __restrict__ Ko,
                                              u16* __restrict__ Vto) {
  int bid = blockIdx.x;
  int sc = bid & 7, h = (bid >> 3) & 31, b = bid >> 8;
  int t = threadIdx.x;
  int sl = t >> 2, c = t & 3;
  int s = sc * 64 + sl;
  __shared__ u16 vt[128][88];
  const u16* base = qkv + (size_t)(b * 512 + s) * 12288 + h * 384;
  int dbase = c * 32, pbase = dbase ^ 64;
  int j0 = dbase & 63;
  float sgn = (c < 2) ? -1.f : 1.f;
  size_t qkbase = ((size_t)(b * 32 + h) * 512 + s) * 128;
#pragma unroll
  for (int g = 0; g < 4; ++g) {
    u16x8 q1 = *(const u16x8*)(base + dbase + g * 8);
    u16x8 q2 = *(const u16x8*)(base + pbase + g * 8);
    u16x8 k1 = *(const u16x8*)(base + 128 + dbase + g * 8);
    u16x8 k2 = *(const u16x8*)(base + 128 + pbase + g * 8);
    u16x8 vv = *(const u16x8*)(base + 256 + dbase + g * 8);
    u16x8 oq, ok;
#pragma unroll
    for (int i = 0; i < 8; ++i) {
      float j = (float)(j0 + g * 8 + i);
      float ang = (float)s * __expf(j * -0.14391156831f);  // ln(10000)/64
      float sv, cv; __sincosf(ang, &sv, &cv);
      oq[i] = f2bf((bf2f(q1[i]) * cv + sgn * bf2f(q2[i]) * sv) * 0.08838834765f);
      ok[i] = f2bf(bf2f(k1[i]) * cv + sgn * bf2f(k2[i]) * sv);
      vt[dbase + g * 8 + i][sl] = vv[i];
    }
    *(u16x8*)(Qo + qkbase + dbase + g * 8) = oq;
    *(u16x8*)(Ko + qkbase + dbase + g * 8) = ok;
  }
  __syncthreads();
  int d = t & 127, s2 = (t >> 7) * 32;
  size_t vb = ((size_t)(b * 32 + h) * 128 + d) * 512 + sc * 64 + s2;
#pragma unroll
  for (int g = 0; g < 4; ++g)
    *(u16x8*)(Vto + vb + g * 8) = *(const u16x8*)&vt[d][s2 + g * 8];
}

// ---------------- causal flash attention ----------------
__global__ __launch_bounds__(256) void k_attn(const u16* __restrict__ Q, const u16* __restrict__ Kg,
                                              const u16* __restrict__ Vt, float* __restrict__ Out) {
  int bid = blockIdx.x;
  int qb = bid & 3, h = (bid >> 2) & 31, b = bid >> 7;
  int t = threadIdx.x, w = t >> 6, lane = t & 63;
  int lr = lane & 15, lg = lane >> 4;
  size_t bh = (size_t)b * 32 + h;
  const u16* Qp = Q + (bh * 512 + qb * 128) * 128;
  const u16* Kp = Kg + bh * 512 * 128;
  const u16* Vp = Vt + bh * 128 * 512;
  __shared__ u16 lK[64][136];
  __shared__ u16 lV[128][88];
  __shared__ u16 lP[4][16][88];
  bf16x8 qf[2][4];
#pragma unroll
  for (int mt = 0; mt < 2; ++mt)
#pragma unroll
    for (int dc = 0; dc < 4; ++dc)
      qf[mt][dc] = *(const bf16x8*)(Qp + (size_t)(w * 32 + mt * 16 + lr) * 128 + dc * 32 + lg * 8);
  f32x4 o[2][8] = {};
  float mrow[2][4], lrow[2][4];
#pragma unroll
  for (int mt = 0; mt < 2; ++mt)
#pragma unroll
    for (int r = 0; r < 4; ++r) { mrow[mt][r] = -1e30f; lrow[mt][r] = 0.f; }
  int q0 = qb * 128;
  for (int kv0 = 0; kv0 < q0 + 128; kv0 += 64) {
    __syncthreads();
#pragma unroll
    for (int p = 0; p < 4; ++p) {
      int idx = t + p * 256;
      int r = idx >> 4, cc = (idx & 15) * 8;
      *(bf16x8*)&lK[r][cc] = *(const bf16x8*)(Kp + (size_t)(kv0 + r) * 128 + cc);
    }
#pragma unroll
    for (int p = 0; p < 4; ++p) {
      int idx = t + p * 256;
      int r = idx >> 3, cc = (idx & 7) * 8;
      *(bf16x8*)&lV[r][cc] = *(const bf16x8*)(Vp + (size_t)r * 512 + kv0 + cc);
    }
    __syncthreads();
    bool diag = (kv0 >= q0);
#pragma unroll
    for (int mt = 0; mt < 2; ++mt) {
      f32x4 sacc[4] = {};
#pragma unroll
      for (int nt = 0; nt < 4; ++nt)
#pragma unroll
        for (int dc = 0; dc < 4; ++dc) {
          bf16x8 kf = *(const bf16x8*)&lK[nt * 16 + lr][dc * 32 + lg * 8];
          sacc[nt] = __builtin_amdgcn_mfma_f32_16x16x32_bf16(qf[mt][dc], kf, sacc[nt], 0, 0, 0);
        }
      int rbase = q0 + w * 32 + mt * 16 + lg * 4;
      if (diag) {
#pragma unroll
        for (int nt = 0; nt < 4; ++nt)
#pragma unroll
          for (int r = 0; r < 4; ++r)
            if (kv0 + nt * 16 + lr > rbase + r) sacc[nt][r] = -1e30f;
      }
#pragma unroll
      for (int r = 0; r < 4; ++r) {
        float mx = fmaxf(fmaxf(sacc[0][r], sacc[1][r]), fmaxf(sacc[2][r], sacc[3][r]));
#pragma unroll
        for (int off = 8; off; off >>= 1) mx = fmaxf(mx, __shfl_xor(mx, off));
        float mold = mrow[mt][r];
        float mnew = fmaxf(mold, mx);
        float alpha = __expf(mold - mnew);
        float ps = 0.f;
#pragma unroll
        for (int nt = 0; nt < 4; ++nt) { float p = __expf(sacc[nt][r] - mnew); sacc[nt][r] = p; ps += p; }
#pragma unroll
        for (int off = 8; off; off >>= 1) ps += __shfl_xor(ps, off);
        mrow[mt][r] = mnew;
        lrow[mt][r] = lrow[mt][r] * alpha + ps;
#pragma unroll
        for (int dt = 0; dt < 8; ++dt) o[mt][dt][r] *= alpha;
      }
#pragma unroll
      for (int nt = 0; nt < 4; ++nt)
#pragma unroll
        for (int r = 0; r < 4; ++r)
          lP[w][lg * 4 + r][nt * 16 + lr] = f2bf(sacc[nt][r]);
#pragma unroll
      for (int kc = 0; kc < 2; ++kc) {
        bf16x8 pf = *(const bf16x8*)&lP[w][lr][kc * 32 + lg * 8];
#pragma unroll
        for (int dt = 0; dt < 8; ++dt) {
          bf16x8 vf = *(const bf16x8*)&lV[dt * 16 + lr][kc * 32 + lg * 8];
          o[mt][dt] = __builtin_amdgcn_mfma_f32_16x16x32_bf16(pf, vf, o[mt][dt], 0, 0, 0);
        }
      }
    }
  }
#pragma unroll
  for (int mt = 0; mt < 2; ++mt)
#pragma unroll
    for (int r = 0; r < 4; ++r) {
      float inv = 1.f / lrow[mt][r];
      int rowg = q0 + w * 32 + mt * 16 + lg * 4 + r;
      size_t ob = ((size_t)b * 512 + rowg) * 4096 + (size_t)h * 128;
#pragma unroll
      for (int dt = 0; dt < 8; ++dt)
        Out[ob + dt * 16 + lr] = o[mt][dt][r] * inv;
    }
}

extern "C" void kernel_launch(void* const* d_in, const int* in_sizes, int n_in,
                              void* d_out, int out_size, void* d_ws, size_t ws_size,
                              hipStream_t stream) {
  const float* X = (const float*)d_in[0];     // [4,512,4096]
  const float* W = (const float*)d_in[1];     // [4096,12288]
  const float* bias = (const float*)d_in[2];  // [12288]
  float* out = (float*)d_out;
  char* ws = (char*)d_ws;
  u16* Xb  = (u16*)(ws);
  u16* Wt  = (u16*)(ws + 16777216);
  u16* qkv = (u16*)(ws + 117440512);
  u16* Qb  = (u16*)(ws);
  u16* Kb  = (u16*)(ws + 16777216);
  u16* Vtb = (u16*)(ws + 33554432);

  k_castx<<<4096, 256, 0, stream>>>(X, Xb);
  k_wtrans<<<dim3(192, 64), 256, 0, stream>>>(W, Wt);
  k_gemm3<<<dim3(48, 16), 512, 0, stream>>>(Xb, Wt, bias, qkv);
  k_rope<<<1024, 256, 0, stream>>>(qkv, Qb, Kb, Vtb);
  k_attn<<<512, 256, 0, stream>>>(Qb, Kb, Vtb, out);
}

// Round 4
// 331.151 us; speedup vs baseline: 1.3667x; 1.0602x over previous
//
#include <hip/hip_runtime.h>

typedef unsigned short u16;
typedef __attribute__((ext_vector_type(8))) __bf16 bf16x8;
typedef __attribute__((ext_vector_type(4))) float f32x4;
typedef __attribute__((ext_vector_type(4))) float f4;
typedef __attribute__((ext_vector_type(8))) unsigned short u16x8;
typedef __attribute__((ext_vector_type(4))) unsigned short u16x4;

__device__ __forceinline__ u16 f2bf(float f) {
  union { float f; unsigned int u; } x; x.f = f;
  unsigned int r = x.u + 0x7FFFu + ((x.u >> 16) & 1u);
  return (u16)(r >> 16);
}
__device__ __forceinline__ float bf2f(u16 h) {
  union { unsigned int u; float f; } x; x.u = ((unsigned int)h) << 16;
  return x.f;
}

typedef const __attribute__((address_space(1))) void* gas_t;
typedef __attribute__((address_space(3))) void* las_t;
__device__ __forceinline__ void gload_lds16(const void* g, void* l) {
  __builtin_amdgcn_global_load_lds((gas_t)g, (las_t)l, 16, 0, 0);
}

#define WAITL0 do { asm volatile("s_waitcnt lgkmcnt(0)" ::: "memory"); \
                    __builtin_amdgcn_sched_barrier(0); } while (0)

// ---------------- cast X fp32 -> bf16 ----------------
__global__ __launch_bounds__(256) void k_castx(const float* __restrict__ X, u16* __restrict__ Xb) {
  int i = blockIdx.x * 256 + threadIdx.x;          // 8 floats per thread
  const f4* src = (const f4*)X + (size_t)i * 2;
  f4 a = src[0], b = src[1];
  u16x8 o;
#pragma unroll
  for (int j = 0; j < 4; ++j) { o[j] = f2bf(a[j]); o[4 + j] = f2bf(b[j]); }
  *((u16x8*)Xb + i) = o;
}

// ---------------- transpose+cast W [4096][12288] fp32 -> Wt [12288][4096] bf16 ----
__global__ __launch_bounds__(256) void k_wtrans(const float* __restrict__ W, u16* __restrict__ Wt) {
  const int N = 12288, K = 4096;
  int n0 = blockIdx.x * 64;
  int k0 = blockIdx.y * 64;
  int t = threadIdx.x;
  __shared__ float tile[64][65];
  int tr = t >> 4;           // 0..15
  int tc4 = (t & 15) * 4;    // 0..60
#pragma unroll
  for (int p = 0; p < 4; ++p) {
    int k = k0 + p * 16 + tr;
    f4 v = *(const f4*)&W[(size_t)k * N + n0 + tc4];
#pragma unroll
    for (int j = 0; j < 4; ++j) tile[p * 16 + tr][tc4 + j] = v[j];
  }
  __syncthreads();
#pragma unroll
  for (int p = 0; p < 4; ++p) {
    int n = n0 + p * 16 + tr;
    u16x4 o;
#pragma unroll
    for (int j = 0; j < 4; ++j) o[j] = f2bf(tile[tc4 + j][p * 16 + tr]);
    *(u16x4*)&Wt[(size_t)n * K + k0 + tc4] = o;
  }
}

// ---------------- GEMM: qkv[2048][12288] = Xb @ Wt^T + bias (bf16 out) ----------
#define MFMA8(FA, FB, IB, JB)                                              \
  _Pragma("unroll")                                                        \
  for (int i2 = 0; i2 < 2; ++i2)                                           \
    _Pragma("unroll")                                                      \
    for (int j2 = 0; j2 < 2; ++j2)                                         \
      _Pragma("unroll")                                                    \
      for (int kk = 0; kk < 2; ++kk)                                       \
        acc[(IB) + i2][(JB) + j2] = __builtin_amdgcn_mfma_f32_16x16x32_bf16( \
            FA[i2][kk], FB[j2][kk], acc[(IB) + i2][(JB) + j2], 0, 0, 0);

#define TILE_BODY(U, STAGE, VMN, CROSS)                                     \
  {                                                                         \
    const int s_ = (U) % 3, sn_ = ((U) + 1) % 3, s2_ = ((U) + 2) % 3;       \
    const size_t kc_ = (size_t)((U) + 2) * 64;                              \
    /* ---- P0 ---- */                                                      \
    WAITL0;                                                                 \
    __builtin_amdgcn_s_setprio(1); MFMA8(fA0, fB0, 0, 0);                   \
    __builtin_amdgcn_s_setprio(0);                                          \
    if (STAGE) {                                                            \
      gload_lds16(aS + kc_,         &lds[s2_ * 24576 + (w * 16) * 64]);     \
      gload_lds16(aS + 8 * K + kc_, &lds[s2_ * 24576 + (w * 16 + 8) * 64]); \
    }                                                                       \
    _Pragma("unroll") for (int j2 = 0; j2 < 2; ++j2)                        \
      _Pragma("unroll") for (int kk = 0; kk < 2; ++kk)                      \
        fB1[j2][kk] = *(const bf16x8*)&lds[s_ * 24576 + bBase + (2 + j2) * 1024 + ch[kk]]; \
    /* ---- P1 ---- */                                                      \
    WAITL0;                                                                 \
    __builtin_amdgcn_s_setprio(1); MFMA8(fA0, fB1, 0, 2);                   \
    __builtin_amdgcn_s_setprio(0);                                          \
    if (STAGE) {                                                            \
      gload_lds16(bS + kc_,         &lds[s2_ * 24576 + 8192 + (w * 32) * 64]); \
      gload_lds16(bS + 8 * K + kc_, &lds[s2_ * 24576 + 8192 + (w * 32 + 8) * 64]); \
    }                                                                       \
    _Pragma("unroll") for (int i2 = 0; i2 < 2; ++i2)                        \
      _Pragma("unroll") for (int kk = 0; kk < 2; ++kk)                      \
        fA1[i2][kk] = *(const bf16x8*)&lds[s_ * 24576 + aBase + (2 + i2) * 1024 + ch[kk]]; \
    /* ---- P2 ---- */                                                      \
    WAITL0;                                                                 \
    __builtin_amdgcn_s_setprio(1); MFMA8(fA1, fB1, 2, 2);                   \
    __builtin_amdgcn_s_setprio(0);                                          \
    if (STAGE) {                                                            \
      gload_lds16(bS + 16 * K + kc_, &lds[s2_ * 24576 + 8192 + (w * 32 + 16) * 64]); \
      gload_lds16(bS + 24 * K + kc_, &lds[s2_ * 24576 + 8192 + (w * 32 + 24) * 64]); \
    }                                                                       \
    if ((VMN) == 6)      { asm volatile("s_waitcnt vmcnt(6)" ::: "memory"); } \
    else if ((VMN) == 0) { asm volatile("s_waitcnt vmcnt(0)" ::: "memory"); } \
    if (CROSS) {                                                            \
      __builtin_amdgcn_s_barrier();                                         \
      _Pragma("unroll") for (int i2 = 0; i2 < 2; ++i2)                      \
        _Pragma("unroll") for (int kk = 0; kk < 2; ++kk)                    \
          fA0[i2][kk] = *(const bf16x8*)&lds[sn_ * 24576 + aBase + i2 * 1024 + ch[kk]]; \
    }                                                                       \
    /* ---- P3 ---- */                                                      \
    __builtin_amdgcn_s_setprio(1); MFMA8(fA1, fB0, 2, 0);                   \
    __builtin_amdgcn_s_setprio(0);                                          \
    if (CROSS) {                                                            \
      _Pragma("unroll") for (int j2 = 0; j2 < 2; ++j2)                      \
        _Pragma("unroll") for (int kk = 0; kk < 2; ++kk)                    \
          fB0[j2][kk] = *(const bf16x8*)&lds[sn_ * 24576 + bBase + j2 * 1024 + ch[kk]]; \
    }                                                                       \
  }

__global__ __launch_bounds__(512) void k_gemm3(const u16* __restrict__ A, const u16* __restrict__ Bt,
                                               const float* __restrict__ bias, u16* __restrict__ C) {
  const int K = 4096, N = 12288;
  const int bn = blockIdx.x, bm = blockIdx.y;    // 48 x 16, bn-fast rasterization
  const int t = threadIdx.x, w = t >> 6, lane = t & 63;
  const int lr = lane & 15, lg = lane >> 4;
  const int wm = w >> 2, wn = w & 3;
  __shared__ u16 lds[3 * 24576];                 // slab: A[128][64] @0, B[256][64] @8192

  f32x4 acc[4][4] = {};
  bf16x8 fA0[2][2], fA1[2][2], fB0[2][2], fB1[2][2];   // [sub][kk]

  const int r8 = lane >> 3;
  const int cgs = (lane & 7) ^ r8;
  const u16* aS = A  + (size_t)(bm * 128 + w * 16 + r8) * K + cgs * 8;
  const u16* bS = Bt + (size_t)(bn * 256 + w * 32 + r8) * K + cgs * 8;

  const int aBase = (wm * 64 + lr) * 64;
  const int bBase = 8192 + (wn * 64 + lr) * 64;
  const int ch[2] = { ((lg ^ (lr & 7)) * 8), (((4 + lg) ^ (lr & 7)) * 8) };

#pragma unroll
  for (int tt = 0; tt < 2; ++tt) {
    gload_lds16(aS + tt * 64,         &lds[tt * 24576 + (w * 16) * 64]);
    gload_lds16(aS + 8 * K + tt * 64, &lds[tt * 24576 + (w * 16 + 8) * 64]);
#pragma unroll
    for (int p = 0; p < 4; ++p)
      gload_lds16(bS + p * 8 * K + tt * 64, &lds[tt * 24576 + 8192 + (w * 32 + p * 8) * 64]);
  }
  asm volatile("s_waitcnt vmcnt(6)" ::: "memory");
  __builtin_amdgcn_s_barrier();
#pragma unroll
  for (int i2 = 0; i2 < 2; ++i2)
#pragma unroll
    for (int kk = 0; kk < 2; ++kk) {
      fA0[i2][kk] = *(const bf16x8*)&lds[aBase + i2 * 1024 + ch[kk]];
      fB0[i2][kk] = *(const bf16x8*)&lds[bBase + i2 * 1024 + ch[kk]];
    }

  for (int u = 0; u < 62; ++u) TILE_BODY(u, true, 6, true);
  TILE_BODY(62, false, 0, true);
  TILE_BODY(63, false, -1, false);

  const int row0b = bm * 128 + wm * 64;
  const int col0b = bn * 256 + wn * 64;
#pragma unroll
  for (int i = 0; i < 4; ++i) {
    int row0 = row0b + i * 16 + lg * 4;
#pragma unroll
    for (int j = 0; j < 4; ++j) {
      int col = col0b + j * 16 + lr;
      float bv = bias[col];
#pragma unroll
      for (int r = 0; r < 4; ++r)
        C[(size_t)(row0 + r) * N + col] = f2bf(acc[i][j][r] + bv);
    }
  }
}

// ---------------- RoPE + split/reshape: qkv bf16 -> Q (scaled), K, Vt ----------
__global__ __launch_bounds__(256) void k_rope(const u16* __restrict__ qkv,
                                              u16* __restrict__ Qo, u16* __restrict__ Ko,
                                              u16* __restrict__ Vto) {
  int bid = blockIdx.x;
  int sc = bid & 7, h = (bid >> 3) & 31, b = bid >> 8;
  int t = threadIdx.x;
  int sl = t >> 2, c = t & 3;
  int s = sc * 64 + sl;
  __shared__ u16 vt[128][88];
  const u16* base = qkv + (size_t)(b * 512 + s) * 12288 + h * 384;
  int dbase = c * 32, pbase = dbase ^ 64;
  int j0 = dbase & 63;
  float sgn = (c < 2) ? -1.f : 1.f;
  size_t qkbase = ((size_t)(b * 32 + h) * 512 + s) * 128;
#pragma unroll
  for (int g = 0; g < 4; ++g) {
    u16x8 q1 = *(const u16x8*)(base + dbase + g * 8);
    u16x8 q2 = *(const u16x8*)(base + pbase + g * 8);
    u16x8 k1 = *(const u16x8*)(base + 128 + dbase + g * 8);
    u16x8 k2 = *(const u16x8*)(base + 128 + pbase + g * 8);
    u16x8 vv = *(const u16x8*)(base + 256 + dbase + g * 8);
    u16x8 oq, ok;
#pragma unroll
    for (int i = 0; i < 8; ++i) {
      float j = (float)(j0 + g * 8 + i);
      float ang = (float)s * __expf(j * -0.14391156831f);  // ln(10000)/64
      float sv, cv; __sincosf(ang, &sv, &cv);
      oq[i] = f2bf((bf2f(q1[i]) * cv + sgn * bf2f(q2[i]) * sv) * 0.08838834765f);
      ok[i] = f2bf(bf2f(k1[i]) * cv + sgn * bf2f(k2[i]) * sv);
      vt[dbase + g * 8 + i][sl] = vv[i];
    }
    *(u16x8*)(Qo + qkbase + dbase + g * 8) = oq;
    *(u16x8*)(Ko + qkbase + dbase + g * 8) = ok;
  }
  __syncthreads();
  int d = t & 127, s2 = (t >> 7) * 32;
  size_t vb = ((size_t)(b * 32 + h) * 128 + d) * 512 + sc * 64 + s2;
#pragma unroll
  for (int g = 0; g < 4; ++g)
    *(u16x8*)(Vto + vb + g * 8) = *(const u16x8*)&vt[d][s2 + g * 8];
}

// ---------------- causal flash attention v2 ----------------
// QBLK=64, 1024 blocks; 4 waves x 16 interleaved q-rows (row = qb*64 + rit*4 + w);
// K double-buffered + V early-issued via global_load_lds (swizzled, pre-swizzled src);
// 2 barriers/tile; defer-max (THR=8); setprio around MFMA clusters.
__global__ __launch_bounds__(256) void k_attn2(const u16* __restrict__ Q, const u16* __restrict__ Kg,
                                               const u16* __restrict__ Vt, float* __restrict__ Out) {
  int bid = blockIdx.x;
  int qb = bid & 7, h = (bid >> 3) & 31, b = bid >> 8;
  int t = threadIdx.x, w = t >> 6, lane = t & 63;
  int lr = lane & 15, lg = lane >> 4;
  size_t bh = (size_t)b * 32 + h;
  const u16* Qp = Q + (bh * 512 + qb * 64) * 128;
  const u16* Kp = Kg + bh * 512 * 128;
  const u16* Vp = Vt + bh * 128 * 512;
  __shared__ u16 lK[2][8192];     // [64][128] swizzled (chunk16 ^= row&7)
  __shared__ u16 lV[8192];        // [128][64] swizzled (chunk8  ^= row&7)
  __shared__ u16 lP[4][16 * 72];  // per-wave, padded

  bf16x8 qf[4];
#pragma unroll
  for (int dc = 0; dc < 4; ++dc)
    qf[dc] = *(const bf16x8*)(Qp + (size_t)(lr * 4 + w) * 128 + dc * 32 + lg * 8);

  f32x4 o[8] = {};
  float m[4], l[4];
#pragma unroll
  for (int r = 0; r < 4; ++r) { m[r] = -1e30f; l[r] = 0.f; }

  const int ntiles = qb + 1;
  // prologue: stage K tile 0 into lK[0]
#pragma unroll
  for (int p = 0; p < 4; ++p) {
    int row = w * 16 + p * 4 + (lane >> 4);
    int ck = (lane & 15) ^ (row & 7);
    gload_lds16(Kp + (size_t)row * 128 + ck * 8, &lK[0][(w * 16 + p * 4) * 128]);
  }
  asm volatile("s_waitcnt vmcnt(0)" ::: "memory");
  __builtin_amdgcn_s_barrier();
  __builtin_amdgcn_sched_barrier(0);

  for (int u = 0; u < ntiles; ++u) {
    const int kv0 = u * 64;
    const int kb = u & 1;
    // issue V for this tile (consumed after mid-tile barrier)
#pragma unroll
    for (int p = 0; p < 4; ++p) {
      int row = w * 32 + p * 8 + (lane >> 3);
      int cv = (lane & 7) ^ ((lane >> 3) & 7);
      gload_lds16(Vp + (size_t)row * 512 + kv0 + cv * 8, &lV[(w * 32 + p * 8) * 64]);
    }
    // issue K for next tile
    if (u + 1 < ntiles) {
#pragma unroll
      for (int p = 0; p < 4; ++p) {
        int row = w * 16 + p * 4 + (lane >> 4);
        int ck = (lane & 15) ^ (row & 7);
        gload_lds16(Kp + (size_t)(kv0 + 64 + row) * 128 + ck * 8, &lK[kb ^ 1][(w * 16 + p * 4) * 128]);
      }
    }
    // QK^T from resident buffer
    f32x4 sacc[4] = {};
    __builtin_amdgcn_s_setprio(1);
#pragma unroll
    for (int nt = 0; nt < 4; ++nt)
#pragma unroll
      for (int dc = 0; dc < 4; ++dc) {
        bf16x8 kf = *(const bf16x8*)&lK[kb][(nt * 16 + lr) * 128 + (((dc * 4 + lg) ^ (lr & 7)) * 8)];
        sacc[nt] = __builtin_amdgcn_mfma_f32_16x16x32_bf16(qf[dc], kf, sacc[nt], 0, 0, 0);
      }
    __builtin_amdgcn_s_setprio(0);
    if (u == ntiles - 1) {   // only the diagonal tile is partial (rows interleaved by 4)
#pragma unroll
      for (int nt = 0; nt < 4; ++nt)
#pragma unroll
        for (int r = 0; r < 4; ++r)
          if (kv0 + nt * 16 + lr > qb * 64 + (lg * 4 + r) * 4 + w) sacc[nt][r] = -1e30f;
    }
    // row max (in-lane over nt, then 16-lane shfl tree)
    float mx[4];
#pragma unroll
    for (int r = 0; r < 4; ++r) {
      float v = fmaxf(fmaxf(sacc[0][r], sacc[1][r]), fmaxf(sacc[2][r], sacc[3][r]));
#pragma unroll
      for (int off = 8; off; off >>= 1) v = fmaxf(v, __shfl_xor(v, off));
      mx[r] = v;
    }
    // defer-max (T13): skip O/l rescale while max growth <= 8
    int needs = (mx[0] > m[0] + 8.f) | (mx[1] > m[1] + 8.f) |
                (mx[2] > m[2] + 8.f) | (mx[3] > m[3] + 8.f);
    if (__any(needs)) {
#pragma unroll
      for (int r = 0; r < 4; ++r) {
        float mn = fmaxf(m[r], mx[r]);
        float a = __expf(m[r] - mn);
        m[r] = mn; l[r] *= a;
#pragma unroll
        for (int dt = 0; dt < 8; ++dt) o[dt][r] *= a;
      }
    }
#pragma unroll
    for (int r = 0; r < 4; ++r) {
      float ps = 0.f;
#pragma unroll
      for (int nt = 0; nt < 4; ++nt) {
        float p = __expf(sacc[nt][r] - m[r]);
        sacc[nt][r] = p; ps += p;
      }
#pragma unroll
      for (int off = 8; off; off >>= 1) ps += __shfl_xor(ps, off);
      l[r] += ps;
    }
    // P -> per-wave LDS (bf16)
#pragma unroll
    for (int nt = 0; nt < 4; ++nt)
#pragma unroll
      for (int r = 0; r < 4; ++r)
        lP[w][(lg * 4 + r) * 72 + nt * 16 + lr] = f2bf(sacc[nt][r]);
    asm volatile("s_waitcnt vmcnt(0)" ::: "memory");
    __builtin_amdgcn_s_barrier();          // V (and next K) collectively resident
    __builtin_amdgcn_sched_barrier(0);
    // PV
    __builtin_amdgcn_s_setprio(1);
#pragma unroll
    for (int kc = 0; kc < 2; ++kc) {
      bf16x8 pf = *(const bf16x8*)&lP[w][lr * 72 + kc * 32 + lg * 8];
#pragma unroll
      for (int dt = 0; dt < 8; ++dt) {
        bf16x8 vf = *(const bf16x8*)&lV[(dt * 16 + lr) * 64 + (((kc * 4 + lg) ^ (lr & 7)) * 8)];
        o[dt] = __builtin_amdgcn_mfma_f32_16x16x32_bf16(pf, vf, o[dt], 0, 0, 0);
      }
    }
    __builtin_amdgcn_s_setprio(0);
    __builtin_amdgcn_s_barrier();          // lV reads drained -> safe to restage next tile
    __builtin_amdgcn_sched_barrier(0);
  }
#pragma unroll
  for (int r = 0; r < 4; ++r) {
    float inv = 1.f / l[r];
    int row = qb * 64 + (lg * 4 + r) * 4 + w;
    size_t ob = ((size_t)b * 512 + row) * 4096 + (size_t)h * 128;
#pragma unroll
    for (int dt = 0; dt < 8; ++dt)
      Out[ob + dt * 16 + lr] = o[dt][r] * inv;
  }
}

extern "C" void kernel_launch(void* const* d_in, const int* in_sizes, int n_in,
                              void* d_out, int out_size, void* d_ws, size_t ws_size,
                              hipStream_t stream) {
  const float* X = (const float*)d_in[0];     // [4,512,4096]
  const float* W = (const float*)d_in[1];     // [4096,12288]
  const float* bias = (const float*)d_in[2];  // [12288]
  float* out = (float*)d_out;
  char* ws = (char*)d_ws;
  u16* Xb  = (u16*)(ws);
  u16* Wt  = (u16*)(ws + 16777216);
  u16* qkv = (u16*)(ws + 117440512);
  u16* Qb  = (u16*)(ws);
  u16* Kb  = (u16*)(ws + 16777216);
  u16* Vtb = (u16*)(ws + 33554432);

  k_castx<<<4096, 256, 0, stream>>>(X, Xb);
  k_wtrans<<<dim3(192, 64), 256, 0, stream>>>(W, Wt);
  k_gemm3<<<dim3(48, 16), 512, 0, stream>>>(Xb, Wt, bias, qkv);
  k_rope<<<1024, 256, 0, stream>>>(qkv, Qb, Kb, Vtb);
  k_attn2<<<1024, 256, 0, stream>>>(Qb, Kb, Vtb, out);
}

// Round 5
// 324.961 us; speedup vs baseline: 1.3927x; 1.0190x over previous
//
#include <hip/hip_runtime.h>

typedef unsigned short u16;
typedef __attribute__((ext_vector_type(8))) __bf16 bf16x8;
typedef __attribute__((ext_vector_type(4))) float f32x4;
typedef __attribute__((ext_vector_type(4))) float f4;
typedef __attribute__((ext_vector_type(8))) unsigned short u16x8;
typedef __attribute__((ext_vector_type(4))) unsigned short u16x4;

__device__ __forceinline__ u16 f2bf(float f) {
  union { float f; unsigned int u; } x; x.f = f;
  unsigned int r = x.u + 0x7FFFu + ((x.u >> 16) & 1u);
  return (u16)(r >> 16);
}
__device__ __forceinline__ float bf2f(u16 h) {
  union { unsigned int u; float f; } x; x.u = ((unsigned int)h) << 16;
  return x.f;
}

typedef const __attribute__((address_space(1))) void* gas_t;
typedef __attribute__((address_space(3))) void* las_t;
__device__ __forceinline__ void gload_lds16(const void* g, void* l) {
  __builtin_amdgcn_global_load_lds((gas_t)g, (las_t)l, 16, 0, 0);
}

#define WAITL0 do { asm volatile("s_waitcnt lgkmcnt(0)" ::: "memory"); \
                    __builtin_amdgcn_sched_barrier(0); } while (0)

// ---------------- cast X fp32 -> bf16 ----------------
__global__ __launch_bounds__(256) void k_castx(const float* __restrict__ X, u16* __restrict__ Xb) {
  int i = blockIdx.x * 256 + threadIdx.x;          // 8 floats per thread
  const f4* src = (const f4*)X + (size_t)i * 2;
  f4 a = src[0], b = src[1];
  u16x8 o;
#pragma unroll
  for (int j = 0; j < 4; ++j) { o[j] = f2bf(a[j]); o[4 + j] = f2bf(b[j]); }
  *((u16x8*)Xb + i) = o;
}

// ---------------- transpose+cast W [4096][12288] fp32 -> Wt [12288][4096] bf16 ----
__global__ __launch_bounds__(256) void k_wtrans(const float* __restrict__ W, u16* __restrict__ Wt) {
  const int N = 12288, K = 4096;
  int n0 = blockIdx.x * 64;
  int k0 = blockIdx.y * 64;
  int t = threadIdx.x;
  __shared__ float tile[64][65];
  int tr = t >> 4;           // 0..15
  int tc4 = (t & 15) * 4;    // 0..60
#pragma unroll
  for (int p = 0; p < 4; ++p) {
    int k = k0 + p * 16 + tr;
    f4 v = *(const f4*)&W[(size_t)k * N + n0 + tc4];
#pragma unroll
    for (int j = 0; j < 4; ++j) tile[p * 16 + tr][tc4 + j] = v[j];
  }
  __syncthreads();
#pragma unroll
  for (int p = 0; p < 4; ++p) {
    int n = n0 + p * 16 + tr;
    u16x4 o;
#pragma unroll
    for (int j = 0; j < 4; ++j) o[j] = f2bf(tile[tc4 + j][p * 16 + tr]);
    *(u16x4*)&Wt[(size_t)n * K + k0 + tc4] = o;
  }
}

// ---------------- GEMM: qkv[2048][12288] = Xb @ Wt^T + bias (bf16 out) ----------
// BM=128, BN=256, BK=64; 8 waves (2Mx4N); 3-slab pipeline; phases ordered so
// every ds_read group hides under >=1 MFMA cluster; counted lgkm/vmcnt waits.
#define MFMA8(FA, FB, IB, JB)                                              \
  _Pragma("unroll")                                                        \
  for (int i2 = 0; i2 < 2; ++i2)                                           \
    _Pragma("unroll")                                                      \
    for (int j2 = 0; j2 < 2; ++j2)                                         \
      _Pragma("unroll")                                                    \
      for (int kk = 0; kk < 2; ++kk)                                       \
        acc[(IB) + i2][(JB) + j2] = __builtin_amdgcn_mfma_f32_16x16x32_bf16( \
            FA[i2][kk], FB[j2][kk], acc[(IB) + i2][(JB) + j2], 0, 0, 0);

// SA = slab of tile U; SB = slab of tile U+1; SC = slab written for tile U+2.
#define TILE_BODY(U, SA, SB, SC, STAGE, VMN, CROSS)                         \
  {                                                                         \
    const size_t kc_ = (size_t)((U) + 2) * 64;                              \
    /* ---- P0: A0xB0 (both prefetched last tile) ---- */                   \
    WAITL0;                                                                 \
    _Pragma("unroll") for (int j2 = 0; j2 < 2; ++j2)                        \
      _Pragma("unroll") for (int kk = 0; kk < 2; ++kk)                      \
        fB1[j2][kk] = *(const bf16x8*)&lds[(SA) * 24576 + bBase + (2 + j2) * 1024 + ch[kk]]; \
    __builtin_amdgcn_sched_barrier(0);                                      \
    __builtin_amdgcn_s_setprio(1); MFMA8(fA0, fB0, 0, 0);                   \
    __builtin_amdgcn_s_setprio(0);                                          \
    _Pragma("unroll") for (int i2 = 0; i2 < 2; ++i2)                        \
      _Pragma("unroll") for (int kk = 0; kk < 2; ++kk)                      \
        fA1[i2][kk] = *(const bf16x8*)&lds[(SA) * 24576 + aBase + (2 + i2) * 1024 + ch[kk]]; \
    if (STAGE) {                                                            \
      gload_lds16(aS + kc_,         &lds[(SC) * 24576 + (w * 16) * 64]);    \
      gload_lds16(aS + 8 * K + kc_, &lds[(SC) * 24576 + (w * 16 + 8) * 64]);\
    }                                                                       \
    /* ---- P1: A0xB1 (B1 drained, A1 may fly; DS in-order) ---- */         \
    asm volatile("s_waitcnt lgkmcnt(4)" ::: "memory");                      \
    __builtin_amdgcn_sched_barrier(0);                                      \
    __builtin_amdgcn_s_setprio(1); MFMA8(fA0, fB1, 0, 2);                   \
    __builtin_amdgcn_s_setprio(0);                                          \
    if (STAGE) {                                                            \
      gload_lds16(bS + kc_,         &lds[(SC) * 24576 + 8192 + (w * 32) * 64]); \
      gload_lds16(bS + 8 * K + kc_, &lds[(SC) * 24576 + 8192 + (w * 32 + 8) * 64]); \
    }                                                                       \
    /* ---- P2: A1xB0 ---- */                                               \
    WAITL0;                                                                 \
    __builtin_amdgcn_s_setprio(1); MFMA8(fA1, fB0, 2, 0);                   \
    __builtin_amdgcn_s_setprio(0);                                          \
    if (STAGE) {                                                            \
      gload_lds16(bS + 16 * K + kc_, &lds[(SC) * 24576 + 8192 + (w * 32 + 16) * 64]); \
      gload_lds16(bS + 24 * K + kc_, &lds[(SC) * 24576 + 8192 + (w * 32 + 24) * 64]); \
    }                                                                       \
    if ((VMN) == 6)      { asm volatile("s_waitcnt vmcnt(6)" ::: "memory"); } \
    else if ((VMN) == 0) { asm volatile("s_waitcnt vmcnt(0)" ::: "memory"); } \
    if (CROSS) {                                                            \
      __builtin_amdgcn_s_barrier();                                         \
      __builtin_amdgcn_sched_barrier(0);                                    \
      _Pragma("unroll") for (int i2 = 0; i2 < 2; ++i2)                      \
        _Pragma("unroll") for (int kk = 0; kk < 2; ++kk) {                  \
          fA0[i2][kk] = *(const bf16x8*)&lds[(SB) * 24576 + aBase + i2 * 1024 + ch[kk]]; \
          fB0[i2][kk] = *(const bf16x8*)&lds[(SB) * 24576 + bBase + i2 * 1024 + ch[kk]]; \
        }                                                                   \
      __builtin_amdgcn_sched_barrier(0);                                    \
    }                                                                       \
    /* ---- P3: A1xB1 (all operands resident; prefetch hides here) ---- */  \
    __builtin_amdgcn_s_setprio(1); MFMA8(fA1, fB1, 2, 2);                   \
    __builtin_amdgcn_s_setprio(0);                                          \
  }

__global__ __launch_bounds__(512) void k_gemm4(const u16* __restrict__ A, const u16* __restrict__ Bt,
                                               const float* __restrict__ bias, u16* __restrict__ C) {
  const int K = 4096, N = 12288;
  const int bn = blockIdx.x, bm = blockIdx.y;    // 48 x 16, bn-fast rasterization
  const int t = threadIdx.x, w = t >> 6, lane = t & 63;
  const int lr = lane & 15, lg = lane >> 4;
  const int wm = w >> 2, wn = w & 3;
  __shared__ u16 lds[3 * 24576];                 // slab: A[128][64] @0, B[256][64] @8192

  f32x4 acc[4][4] = {};
  bf16x8 fA0[2][2], fA1[2][2], fB0[2][2], fB1[2][2];   // [sub][kk]

  const int r8 = lane >> 3;
  const int cgs = (lane & 7) ^ r8;
  const u16* aS = A  + (size_t)(bm * 128 + w * 16 + r8) * K + cgs * 8;
  const u16* bS = Bt + (size_t)(bn * 256 + w * 32 + r8) * K + cgs * 8;

  const int aBase = (wm * 64 + lr) * 64;
  const int bBase = 8192 + (wn * 64 + lr) * 64;
  const int ch[2] = { ((lg ^ (lr & 7)) * 8), (((4 + lg) ^ (lr & 7)) * 8) };

#pragma unroll
  for (int tt = 0; tt < 2; ++tt) {
    gload_lds16(aS + tt * 64,         &lds[tt * 24576 + (w * 16) * 64]);
    gload_lds16(aS + 8 * K + tt * 64, &lds[tt * 24576 + (w * 16 + 8) * 64]);
#pragma unroll
    for (int p = 0; p < 4; ++p)
      gload_lds16(bS + p * 8 * K + tt * 64, &lds[tt * 24576 + 8192 + (w * 32 + p * 8) * 64]);
  }
  asm volatile("s_waitcnt vmcnt(6)" ::: "memory");
  __builtin_amdgcn_s_barrier();
#pragma unroll
  for (int i2 = 0; i2 < 2; ++i2)
#pragma unroll
    for (int kk = 0; kk < 2; ++kk) {
      fA0[i2][kk] = *(const bf16x8*)&lds[aBase + i2 * 1024 + ch[kk]];
      fB0[i2][kk] = *(const bf16x8*)&lds[bBase + i2 * 1024 + ch[kk]];
    }

  for (int v = 0; v < 20; ++v) {
    TILE_BODY(3 * v,     0, 1, 2, true, 6, true)
    TILE_BODY(3 * v + 1, 1, 2, 0, true, 6, true)
    TILE_BODY(3 * v + 2, 2, 0, 1, true, 6, true)
  }
  TILE_BODY(60, 0, 1, 2, true,  6, true)
  TILE_BODY(61, 1, 2, 0, true,  6, true)
  TILE_BODY(62, 2, 0, 1, false, 0, true)
  TILE_BODY(63, 0, 1, 2, false, -1, false)

  const int row0b = bm * 128 + wm * 64;
  const int col0b = bn * 256 + wn * 64;
#pragma unroll
  for (int i = 0; i < 4; ++i) {
    int row0 = row0b + i * 16 + lg * 4;
#pragma unroll
    for (int j = 0; j < 4; ++j) {
      int col = col0b + j * 16 + lr;
      float bv = bias[col];
#pragma unroll
      for (int r = 0; r < 4; ++r)
        C[(size_t)(row0 + r) * N + col] = f2bf(acc[i][j][r] + bv);
    }
  }
}

// ---------------- RoPE + split/reshape: qkv bf16 -> Q (scaled), K, Vt ----------
__global__ __launch_bounds__(256) void k_rope(const u16* __restrict__ qkv,
                                              u16* __restrict__ Qo, u16* __restrict__ Ko,
                                              u16* __restrict__ Vto) {
  int bid = blockIdx.x;
  int sc = bid & 7, h = (bid >> 3) & 31, b = bid >> 8;
  int t = threadIdx.x;
  int sl = t >> 2, c = t & 3;
  int s = sc * 64 + sl;
  __shared__ u16 vt[128][88];
  const u16* base = qkv + (size_t)(b * 512 + s) * 12288 + h * 384;
  int dbase = c * 32, pbase = dbase ^ 64;
  int j0 = dbase & 63;
  float sgn = (c < 2) ? -1.f : 1.f;
  size_t qkbase = ((size_t)(b * 32 + h) * 512 + s) * 128;
#pragma unroll
  for (int g = 0; g < 4; ++g) {
    u16x8 q1 = *(const u16x8*)(base + dbase + g * 8);
    u16x8 q2 = *(const u16x8*)(base + pbase + g * 8);
    u16x8 k1 = *(const u16x8*)(base + 128 + dbase + g * 8);
    u16x8 k2 = *(const u16x8*)(base + 128 + pbase + g * 8);
    u16x8 vv = *(const u16x8*)(base + 256 + dbase + g * 8);
    u16x8 oq, ok;
#pragma unroll
    for (int i = 0; i < 8; ++i) {
      float j = (float)(j0 + g * 8 + i);
      float ang = (float)s * __expf(j * -0.14391156831f);  // ln(10000)/64
      float sv, cv; __sincosf(ang, &sv, &cv);
      oq[i] = f2bf((bf2f(q1[i]) * cv + sgn * bf2f(q2[i]) * sv) * 0.08838834765f);
      ok[i] = f2bf(bf2f(k1[i]) * cv + sgn * bf2f(k2[i]) * sv);
      vt[dbase + g * 8 + i][sl] = vv[i];
    }
    *(u16x8*)(Qo + qkbase + dbase + g * 8) = oq;
    *(u16x8*)(Ko + qkbase + dbase + g * 8) = ok;
  }
  __syncthreads();
  int d = t & 127, s2 = (t >> 7) * 32;
  size_t vb = ((size_t)(b * 32 + h) * 128 + d) * 512 + sc * 64 + s2;
#pragma unroll
  for (int g = 0; g < 4; ++g)
    *(u16x8*)(Vto + vb + g * 8) = *(const u16x8*)&vt[d][s2 + g * 8];
}

// ---------------- causal flash attention v2 ----------------
__global__ __launch_bounds__(256) void k_attn2(const u16* __restrict__ Q, const u16* __restrict__ Kg,
                                               const u16* __restrict__ Vt, float* __restrict__ Out) {
  int bid = blockIdx.x;
  int qb = bid & 7, h = (bid >> 3) & 31, b = bid >> 8;
  int t = threadIdx.x, w = t >> 6, lane = t & 63;
  int lr = lane & 15, lg = lane >> 4;
  size_t bh = (size_t)b * 32 + h;
  const u16* Qp = Q + (bh * 512 + qb * 64) * 128;
  const u16* Kp = Kg + bh * 512 * 128;
  const u16* Vp = Vt + bh * 128 * 512;
  __shared__ u16 lK[2][8192];     // [64][128] swizzled (chunk16 ^= row&7)
  __shared__ u16 lV[8192];        // [128][64] swizzled (chunk8  ^= row&7)
  __shared__ u16 lP[4][16 * 72];  // per-wave, padded

  bf16x8 qf[4];
#pragma unroll
  for (int dc = 0; dc < 4; ++dc)
    qf[dc] = *(const bf16x8*)(Qp + (size_t)(lr * 4 + w) * 128 + dc * 32 + lg * 8);

  f32x4 o[8] = {};
  float m[4], l[4];
#pragma unroll
  for (int r = 0; r < 4; ++r) { m[r] = -1e30f; l[r] = 0.f; }

  const int ntiles = qb + 1;
#pragma unroll
  for (int p = 0; p < 4; ++p) {
    int row = w * 16 + p * 4 + (lane >> 4);
    int ck = (lane & 15) ^ (row & 7);
    gload_lds16(Kp + (size_t)row * 128 + ck * 8, &lK[0][(w * 16 + p * 4) * 128]);
  }
  asm volatile("s_waitcnt vmcnt(0)" ::: "memory");
  __builtin_amdgcn_s_barrier();
  __builtin_amdgcn_sched_barrier(0);

  for (int u = 0; u < ntiles; ++u) {
    const int kv0 = u * 64;
    const int kb = u & 1;
#pragma unroll
    for (int p = 0; p < 4; ++p) {
      int row = w * 32 + p * 8 + (lane >> 3);
      int cv = (lane & 7) ^ ((lane >> 3) & 7);
      gload_lds16(Vp + (size_t)row * 512 + kv0 + cv * 8, &lV[(w * 32 + p * 8) * 64]);
    }
    if (u + 1 < ntiles) {
#pragma unroll
      for (int p = 0; p < 4; ++p) {
        int row = w * 16 + p * 4 + (lane >> 4);
        int ck = (lane & 15) ^ (row & 7);
        gload_lds16(Kp + (size_t)(kv0 + 64 + row) * 128 + ck * 8, &lK[kb ^ 1][(w * 16 + p * 4) * 128]);
      }
    }
    f32x4 sacc[4] = {};
    __builtin_amdgcn_s_setprio(1);
#pragma unroll
    for (int nt = 0; nt < 4; ++nt)
#pragma unroll
      for (int dc = 0; dc < 4; ++dc) {
        bf16x8 kf = *(const bf16x8*)&lK[kb][(nt * 16 + lr) * 128 + (((dc * 4 + lg) ^ (lr & 7)) * 8)];
        sacc[nt] = __builtin_amdgcn_mfma_f32_16x16x32_bf16(qf[dc], kf, sacc[nt], 0, 0, 0);
      }
    __builtin_amdgcn_s_setprio(0);
    if (u == ntiles - 1) {
#pragma unroll
      for (int nt = 0; nt < 4; ++nt)
#pragma unroll
        for (int r = 0; r < 4; ++r)
          if (kv0 + nt * 16 + lr > qb * 64 + (lg * 4 + r) * 4 + w) sacc[nt][r] = -1e30f;
    }
    float mx[4];
#pragma unroll
    for (int r = 0; r < 4; ++r) {
      float v = fmaxf(fmaxf(sacc[0][r], sacc[1][r]), fmaxf(sacc[2][r], sacc[3][r]));
#pragma unroll
      for (int off = 8; off; off >>= 1) v = fmaxf(v, __shfl_xor(v, off));
      mx[r] = v;
    }
    int needs = (mx[0] > m[0] + 8.f) | (mx[1] > m[1] + 8.f) |
                (mx[2] > m[2] + 8.f) | (mx[3] > m[3] + 8.f);
    if (__any(needs)) {
#pragma unroll
      for (int r = 0; r < 4; ++r) {
        float mn = fmaxf(m[r], mx[r]);
        float a = __expf(m[r] - mn);
        m[r] = mn; l[r] *= a;
#pragma unroll
        for (int dt = 0; dt < 8; ++dt) o[dt][r] *= a;
      }
    }
#pragma unroll
    for (int r = 0; r < 4; ++r) {
      float ps = 0.f;
#pragma unroll
      for (int nt = 0; nt < 4; ++nt) {
        float p = __expf(sacc[nt][r] - m[r]);
        sacc[nt][r] = p; ps += p;
      }
#pragma unroll
      for (int off = 8; off; off >>= 1) ps += __shfl_xor(ps, off);
      l[r] += ps;
    }
#pragma unroll
    for (int nt = 0; nt < 4; ++nt)
#pragma unroll
      for (int r = 0; r < 4; ++r)
        lP[w][(lg * 4 + r) * 72 + nt * 16 + lr] = f2bf(sacc[nt][r]);
    asm volatile("s_waitcnt vmcnt(0)" ::: "memory");
    __builtin_amdgcn_s_barrier();
    __builtin_amdgcn_sched_barrier(0);
    __builtin_amdgcn_s_setprio(1);
#pragma unroll
    for (int kc = 0; kc < 2; ++kc) {
      bf16x8 pf = *(const bf16x8*)&lP[w][lr * 72 + kc * 32 + lg * 8];
#pragma unroll
      for (int dt = 0; dt < 8; ++dt) {
        bf16x8 vf = *(const bf16x8*)&lV[(dt * 16 + lr) * 64 + (((kc * 4 + lg) ^ (lr & 7)) * 8)];
        o[dt] = __builtin_amdgcn_mfma_f32_16x16x32_bf16(pf, vf, o[dt], 0, 0, 0);
      }
    }
    __builtin_amdgcn_s_setprio(0);
    __builtin_amdgcn_s_barrier();
    __builtin_amdgcn_sched_barrier(0);
  }
#pragma unroll
  for (int r = 0; r < 4; ++r) {
    float inv = 1.f / l[r];
    int row = qb * 64 + (lg * 4 + r) * 4 + w;
    size_t ob = ((size_t)b * 512 + row) * 4096 + (size_t)h * 128;
#pragma unroll
    for (int dt = 0; dt < 8; ++dt)
      Out[ob + dt * 16 + lr] = o[dt][r] * inv;
  }
}

extern "C" void kernel_launch(void* const* d_in, const int* in_sizes, int n_in,
                              void* d_out, int out_size, void* d_ws, size_t ws_size,
                              hipStream_t stream) {
  const float* X = (const float*)d_in[0];     // [4,512,4096]
  const float* W = (const float*)d_in[1];     // [4096,12288]
  const float* bias = (const float*)d_in[2];  // [12288]
  float* out = (float*)d_out;
  char* ws = (char*)d_ws;
  u16* Xb  = (u16*)(ws);
  u16* Wt  = (u16*)(ws + 16777216);
  u16* qkv = (u16*)(ws + 117440512);
  u16* Qb  = (u16*)(ws);
  u16* Kb  = (u16*)(ws + 16777216);
  u16* Vtb = (u16*)(ws + 33554432);

  k_castx<<<4096, 256, 0, stream>>>(X, Xb);
  k_wtrans<<<dim3(192, 64), 256, 0, stream>>>(W, Wt);
  k_gemm4<<<dim3(48, 16), 512, 0, stream>>>(Xb, Wt, bias, qkv);
  k_rope<<<1024, 256, 0, stream>>>(qkv, Qb, Kb, Vtb);
  k_attn2<<<1024, 256, 0, stream>>>(Qb, Kb, Vtb, out);
}

// Round 6
// 308.975 us; speedup vs baseline: 1.4648x; 1.0517x over previous
//
#include <hip/hip_runtime.h>

typedef unsigned short u16;
typedef __attribute__((ext_vector_type(8))) __bf16 bf16x8;
typedef __attribute__((ext_vector_type(4))) float f32x4;
typedef __attribute__((ext_vector_type(4))) float f4;
typedef __attribute__((ext_vector_type(8))) unsigned short u16x8;
typedef __attribute__((ext_vector_type(4))) unsigned short u16x4;

__device__ __forceinline__ u16 f2bf(float f) {
  union { float f; unsigned int u; } x; x.f = f;
  unsigned int r = x.u + 0x7FFFu + ((x.u >> 16) & 1u);
  return (u16)(r >> 16);
}
__device__ __forceinline__ float bf2f(u16 h) {
  union { unsigned int u; float f; } x; x.u = ((unsigned int)h) << 16;
  return x.f;
}

typedef const __attribute__((address_space(1))) void* gas_t;
typedef __attribute__((address_space(3))) void* las_t;
__device__ __forceinline__ void gload_lds16(const void* g, void* l) {
  __builtin_amdgcn_global_load_lds((gas_t)g, (las_t)l, 16, 0, 0);
}

#define WAITL0 do { asm volatile("s_waitcnt lgkmcnt(0)" ::: "memory"); \
                    __builtin_amdgcn_sched_barrier(0); } while (0)

// ---------------- cast X fp32 -> bf16 ----------------
__global__ __launch_bounds__(256) void k_castx(const float* __restrict__ X, u16* __restrict__ Xb) {
  int i = blockIdx.x * 256 + threadIdx.x;          // 8 floats per thread
  const f4* src = (const f4*)X + (size_t)i * 2;
  f4 a = src[0], b = src[1];
  u16x8 o;
#pragma unroll
  for (int j = 0; j < 4; ++j) { o[j] = f2bf(a[j]); o[4 + j] = f2bf(b[j]); }
  *((u16x8*)Xb + i) = o;
}

// ---------------- transpose+cast W [4096][12288] fp32 -> Wt [12288][4096] bf16 ----
__global__ __launch_bounds__(256) void k_wtrans(const float* __restrict__ W, u16* __restrict__ Wt) {
  const int N = 12288, K = 4096;
  int n0 = blockIdx.x * 64;
  int k0 = blockIdx.y * 64;
  int t = threadIdx.x;
  __shared__ float tile[64][65];
  int tr = t >> 4;           // 0..15
  int tc4 = (t & 15) * 4;    // 0..60
#pragma unroll
  for (int p = 0; p < 4; ++p) {
    int k = k0 + p * 16 + tr;
    f4 v = *(const f4*)&W[(size_t)k * N + n0 + tc4];
#pragma unroll
    for (int j = 0; j < 4; ++j) tile[p * 16 + tr][tc4 + j] = v[j];
  }
  __syncthreads();
#pragma unroll
  for (int p = 0; p < 4; ++p) {
    int n = n0 + p * 16 + tr;
    u16x4 o;
#pragma unroll
    for (int j = 0; j < 4; ++j) o[j] = f2bf(tile[tc4 + j][p * 16 + tr]);
    *(u16x4*)&Wt[(size_t)n * K + k0 + tc4] = o;
  }
}

// ---------------- GEMM: qkv[2048][12288] = Xb @ Wt^T + bias (bf16 out) ----------
#define MFMA8(FA, FB, IB, JB)                                              \
  _Pragma("unroll")                                                        \
  for (int i2 = 0; i2 < 2; ++i2)                                           \
    _Pragma("unroll")                                                      \
    for (int j2 = 0; j2 < 2; ++j2)                                         \
      _Pragma("unroll")                                                    \
      for (int kk = 0; kk < 2; ++kk)                                       \
        acc[(IB) + i2][(JB) + j2] = __builtin_amdgcn_mfma_f32_16x16x32_bf16( \
            FA[i2][kk], FB[j2][kk], acc[(IB) + i2][(JB) + j2], 0, 0, 0);

// SA = slab of tile U; SB = slab of tile U+1; SC = slab written for tile U+2.
#define TILE_BODY(U, SA, SB, SC, STAGE, VMN, CROSS)                         \
  {                                                                         \
    const size_t kc_ = (size_t)((U) + 2) * 64;                              \
    /* ---- P0: A0xB0 (both prefetched last tile) ---- */                   \
    WAITL0;                                                                 \
    _Pragma("unroll") for (int j2 = 0; j2 < 2; ++j2)                        \
      _Pragma("unroll") for (int kk = 0; kk < 2; ++kk)                      \
        fB1[j2][kk] = *(const bf16x8*)&lds[(SA) * 24576 + bBase + (2 + j2) * 1024 + ch[kk]]; \
    __builtin_amdgcn_sched_barrier(0);                                      \
    __builtin_amdgcn_s_setprio(1); MFMA8(fA0, fB0, 0, 0);                   \
    __builtin_amdgcn_s_setprio(0);                                          \
    _Pragma("unroll") for (int i2 = 0; i2 < 2; ++i2)                        \
      _Pragma("unroll") for (int kk = 0; kk < 2; ++kk)                      \
        fA1[i2][kk] = *(const bf16x8*)&lds[(SA) * 24576 + aBase + (2 + i2) * 1024 + ch[kk]]; \
    if (STAGE) {                                                            \
      gload_lds16(aS + kc_,         &lds[(SC) * 24576 + (w * 16) * 64]);    \
      gload_lds16(aS + 8 * K + kc_, &lds[(SC) * 24576 + (w * 16 + 8) * 64]);\
    }                                                                       \
    /* ---- P1: A0xB1 (B1 drained, A1 may fly; DS in-order) ---- */         \
    asm volatile("s_waitcnt lgkmcnt(4)" ::: "memory");                      \
    __builtin_amdgcn_sched_barrier(0);                                      \
    __builtin_amdgcn_s_setprio(1); MFMA8(fA0, fB1, 0, 2);                   \
    __builtin_amdgcn_s_setprio(0);                                          \
    if (STAGE) {                                                            \
      gload_lds16(bS + kc_,         &lds[(SC) * 24576 + 8192 + (w * 32) * 64]); \
      gload_lds16(bS + 8 * K + kc_, &lds[(SC) * 24576 + 8192 + (w * 32 + 8) * 64]); \
    }                                                                       \
    /* ---- P2: A1xB0 ---- */                                               \
    WAITL0;                                                                 \
    __builtin_amdgcn_s_setprio(1); MFMA8(fA1, fB0, 2, 0);                   \
    __builtin_amdgcn_s_setprio(0);                                          \
    if (STAGE) {                                                            \
      gload_lds16(bS + 16 * K + kc_, &lds[(SC) * 24576 + 8192 + (w * 32 + 16) * 64]); \
      gload_lds16(bS + 24 * K + kc_, &lds[(SC) * 24576 + 8192 + (w * 32 + 24) * 64]); \
    }                                                                       \
    if ((VMN) == 6)      { asm volatile("s_waitcnt vmcnt(6)" ::: "memory"); } \
    else if ((VMN) == 0) { asm volatile("s_waitcnt vmcnt(0)" ::: "memory"); } \
    if (CROSS) {                                                            \
      __builtin_amdgcn_s_barrier();                                         \
      __builtin_amdgcn_sched_barrier(0);                                    \
      _Pragma("unroll") for (int i2 = 0; i2 < 2; ++i2)                      \
        _Pragma("unroll") for (int kk = 0; kk < 2; ++kk) {                  \
          fA0[i2][kk] = *(const bf16x8*)&lds[(SB) * 24576 + aBase + i2 * 1024 + ch[kk]]; \
          fB0[i2][kk] = *(const bf16x8*)&lds[(SB) * 24576 + bBase + i2 * 1024 + ch[kk]]; \
        }                                                                   \
      __builtin_amdgcn_sched_barrier(0);                                    \
    }                                                                       \
    /* ---- P3: A1xB1 (all operands resident; prefetch hides here) ---- */  \
    __builtin_amdgcn_s_setprio(1); MFMA8(fA1, fB1, 2, 2);                   \
    __builtin_amdgcn_s_setprio(0);                                          \
  }

__global__ __launch_bounds__(512) void k_gemm4(const u16* __restrict__ A, const u16* __restrict__ Bt,
                                               const float* __restrict__ bias, u16* __restrict__ C) {
  const int K = 4096, N = 12288;
  const int bn = blockIdx.x, bm = blockIdx.y;    // 48 x 16, bn-fast rasterization
  const int t = threadIdx.x, w = t >> 6, lane = t & 63;
  const int lr = lane & 15, lg = lane >> 4;
  const int wm = w >> 2, wn = w & 3;
  __shared__ u16 lds[3 * 24576];                 // slab: A[128][64] @0, B[256][64] @8192

  f32x4 acc[4][4] = {};
  bf16x8 fA0[2][2], fA1[2][2], fB0[2][2], fB1[2][2];   // [sub][kk]

  const int r8 = lane >> 3;
  const int cgs = (lane & 7) ^ r8;
  const u16* aS = A  + (size_t)(bm * 128 + w * 16 + r8) * K + cgs * 8;
  const u16* bS = Bt + (size_t)(bn * 256 + w * 32 + r8) * K + cgs * 8;

  const int aBase = (wm * 64 + lr) * 64;
  const int bBase = 8192 + (wn * 64 + lr) * 64;
  const int ch[2] = { ((lg ^ (lr & 7)) * 8), (((4 + lg) ^ (lr & 7)) * 8) };

#pragma unroll
  for (int tt = 0; tt < 2; ++tt) {
    gload_lds16(aS + tt * 64,         &lds[tt * 24576 + (w * 16) * 64]);
    gload_lds16(aS + 8 * K + tt * 64, &lds[tt * 24576 + (w * 16 + 8) * 64]);
#pragma unroll
    for (int p = 0; p < 4; ++p)
      gload_lds16(bS + p * 8 * K + tt * 64, &lds[tt * 24576 + 8192 + (w * 32 + p * 8) * 64]);
  }
  asm volatile("s_waitcnt vmcnt(6)" ::: "memory");
  __builtin_amdgcn_s_barrier();
#pragma unroll
  for (int i2 = 0; i2 < 2; ++i2)
#pragma unroll
    for (int kk = 0; kk < 2; ++kk) {
      fA0[i2][kk] = *(const bf16x8*)&lds[aBase + i2 * 1024 + ch[kk]];
      fB0[i2][kk] = *(const bf16x8*)&lds[bBase + i2 * 1024 + ch[kk]];
    }

  for (int v = 0; v < 20; ++v) {
    TILE_BODY(3 * v,     0, 1, 2, true, 6, true)
    TILE_BODY(3 * v + 1, 1, 2, 0, true, 6, true)
    TILE_BODY(3 * v + 2, 2, 0, 1, true, 6, true)
  }
  TILE_BODY(60, 0, 1, 2, true,  6, true)
  TILE_BODY(61, 1, 2, 0, true,  6, true)
  TILE_BODY(62, 2, 0, 1, false, 0, true)
  TILE_BODY(63, 0, 1, 2, false, -1, false)

  const int row0b = bm * 128 + wm * 64;
  const int col0b = bn * 256 + wn * 64;
#pragma unroll
  for (int i = 0; i < 4; ++i) {
    int row0 = row0b + i * 16 + lg * 4;
#pragma unroll
    for (int j = 0; j < 4; ++j) {
      int col = col0b + j * 16 + lr;
      float bv = bias[col];
#pragma unroll
      for (int r = 0; r < 4; ++r)
        C[(size_t)(row0 + r) * N + col] = f2bf(acc[i][j][r] + bv);
    }
  }
}

// ---------------- RoPE + split/reshape: qkv bf16 -> Q (scaled), K, Vt ----------
__global__ __launch_bounds__(256) void k_rope(const u16* __restrict__ qkv,
                                              u16* __restrict__ Qo, u16* __restrict__ Ko,
                                              u16* __restrict__ Vto) {
  int bid = blockIdx.x;
  int sc = bid & 7, h = (bid >> 3) & 31, b = bid >> 8;
  int t = threadIdx.x;
  int sl = t >> 2, c = t & 3;
  int s = sc * 64 + sl;
  __shared__ u16 vt[128][88];
  const u16* base = qkv + (size_t)(b * 512 + s) * 12288 + h * 384;
  int dbase = c * 32, pbase = dbase ^ 64;
  int j0 = dbase & 63;
  float sgn = (c < 2) ? -1.f : 1.f;
  size_t qkbase = ((size_t)(b * 32 + h) * 512 + s) * 128;
#pragma unroll
  for (int g = 0; g < 4; ++g) {
    u16x8 q1 = *(const u16x8*)(base + dbase + g * 8);
    u16x8 q2 = *(const u16x8*)(base + pbase + g * 8);
    u16x8 k1 = *(const u16x8*)(base + 128 + dbase + g * 8);
    u16x8 k2 = *(const u16x8*)(base + 128 + pbase + g * 8);
    u16x8 vv = *(const u16x8*)(base + 256 + dbase + g * 8);
    u16x8 oq, ok;
#pragma unroll
    for (int i = 0; i < 8; ++i) {
      float j = (float)(j0 + g * 8 + i);
      float ang = (float)s * __expf(j * -0.14391156831f);  // ln(10000)/64
      float sv, cv; __sincosf(ang, &sv, &cv);
      oq[i] = f2bf((bf2f(q1[i]) * cv + sgn * bf2f(q2[i]) * sv) * 0.08838834765f);
      ok[i] = f2bf(bf2f(k1[i]) * cv + sgn * bf2f(k2[i]) * sv);
      vt[dbase + g * 8 + i][sl] = vv[i];
    }
    *(u16x8*)(Qo + qkbase + dbase + g * 8) = oq;
    *(u16x8*)(Ko + qkbase + dbase + g * 8) = ok;
  }
  __syncthreads();
  int d = t & 127, s2 = (t >> 7) * 32;
  size_t vb = ((size_t)(b * 32 + h) * 128 + d) * 512 + sc * 64 + s2;
#pragma unroll
  for (int g = 0; g < 4; ++g)
    *(u16x8*)(Vto + vb + g * 8) = *(const u16x8*)&vt[d][s2 + g * 8];
}

// ---------------- causal flash attention v3 ----------------
// 512 blocks; block (pair,bh) handles qb=pair and qb=7-pair sequentially ->
// exactly 9 KV-tiles per block (perfect balance, all blocks co-resident).
// Counted mid-tile vmcnt(4): V resident, K(u+1) still flying; K drains at a
// post-PV vmcnt(0) so its latency hides under softmax+PV instead of stalling.
__global__ __launch_bounds__(256) void k_attn3(const u16* __restrict__ Q, const u16* __restrict__ Kg,
                                               const u16* __restrict__ Vt, float* __restrict__ Out) {
  int bid = blockIdx.x;            // 512
  int pair = bid & 3, bh = bid >> 2;
  int t = threadIdx.x, w = t >> 6, lane = t & 63;
  int lr = lane & 15, lg = lane >> 4;
  int b = bh >> 5, h = bh & 31;
  const u16* Kp = Kg + (size_t)bh * 512 * 128;
  const u16* Vp = Vt + (size_t)bh * 128 * 512;
  __shared__ u16 lK[2][8192];     // [64][128] swizzled (chunk16 ^= row&7)
  __shared__ u16 lV[8192];        // [128][64] swizzled (chunk8  ^= row&7)
  __shared__ u16 lP[4][16 * 72];  // per-wave, padded

  for (int half = 0; half < 2; ++half) {
    const int qb = half ? (7 - pair) : pair;
    const int ntiles = qb + 1;
    const u16* Qp = Q + ((size_t)bh * 512 + qb * 64) * 128;

    bf16x8 qf[4];
#pragma unroll
    for (int dc = 0; dc < 4; ++dc)
      qf[dc] = *(const bf16x8*)(Qp + (size_t)(lr * 4 + w) * 128 + dc * 32 + lg * 8);

    f32x4 o[8] = {};
    float m[4], l[4];
#pragma unroll
    for (int r = 0; r < 4; ++r) { m[r] = -1e30f; l[r] = 0.f; }

    // prologue: stage K tile 0 (safe: previous half's LDS readers drained at its final barrier)
#pragma unroll
    for (int p = 0; p < 4; ++p) {
      int row = w * 16 + p * 4 + (lane >> 4);
      int ck = (lane & 15) ^ (row & 7);
      gload_lds16(Kp + (size_t)row * 128 + ck * 8, &lK[0][(w * 16 + p * 4) * 128]);
    }
    asm volatile("s_waitcnt vmcnt(0)" ::: "memory");
    __builtin_amdgcn_s_barrier();
    __builtin_amdgcn_sched_barrier(0);

    for (int u = 0; u < ntiles; ++u) {
      const int kv0 = u * 64;
      const int kb = u & 1;
      // issue V(u) first (oldest -> drained by vmcnt(4))
#pragma unroll
      for (int p = 0; p < 4; ++p) {
        int row = w * 32 + p * 8 + (lane >> 3);
        int cv = (lane & 7) ^ ((lane >> 3) & 7);
        gload_lds16(Vp + (size_t)row * 512 + kv0 + cv * 8, &lV[(w * 32 + p * 8) * 64]);
      }
      // issue K(u+1) (drained post-PV)
      if (u + 1 < ntiles) {
#pragma unroll
        for (int p = 0; p < 4; ++p) {
          int row = w * 16 + p * 4 + (lane >> 4);
          int ck = (lane & 15) ^ (row & 7);
          gload_lds16(Kp + (size_t)(kv0 + 64 + row) * 128 + ck * 8, &lK[kb ^ 1][(w * 16 + p * 4) * 128]);
        }
      }
      f32x4 sacc[4] = {};
      __builtin_amdgcn_s_setprio(1);
#pragma unroll
      for (int nt = 0; nt < 4; ++nt)
#pragma unroll
        for (int dc = 0; dc < 4; ++dc) {
          bf16x8 kf = *(const bf16x8*)&lK[kb][(nt * 16 + lr) * 128 + (((dc * 4 + lg) ^ (lr & 7)) * 8)];
          sacc[nt] = __builtin_amdgcn_mfma_f32_16x16x32_bf16(qf[dc], kf, sacc[nt], 0, 0, 0);
        }
      __builtin_amdgcn_s_setprio(0);
      if (u == ntiles - 1) {
#pragma unroll
        for (int nt = 0; nt < 4; ++nt)
#pragma unroll
          for (int r = 0; r < 4; ++r)
            if (kv0 + nt * 16 + lr > qb * 64 + (lg * 4 + r) * 4 + w) sacc[nt][r] = -1e30f;
      }
      float mx[4];
#pragma unroll
      for (int r = 0; r < 4; ++r) {
        float v = fmaxf(fmaxf(sacc[0][r], sacc[1][r]), fmaxf(sacc[2][r], sacc[3][r]));
#pragma unroll
        for (int off = 8; off; off >>= 1) v = fmaxf(v, __shfl_xor(v, off));
        mx[r] = v;
      }
      int needs = (mx[0] > m[0] + 8.f) | (mx[1] > m[1] + 8.f) |
                  (mx[2] > m[2] + 8.f) | (mx[3] > m[3] + 8.f);
      if (__any(needs)) {
#pragma unroll
        for (int r = 0; r < 4; ++r) {
          float mn = fmaxf(m[r], mx[r]);
          float a = __expf(m[r] - mn);
          m[r] = mn; l[r] *= a;
#pragma unroll
          for (int dt = 0; dt < 8; ++dt) o[dt][r] *= a;
        }
      }
#pragma unroll
      for (int r = 0; r < 4; ++r) {
        float ps = 0.f;
#pragma unroll
        for (int nt = 0; nt < 4; ++nt) {
          float p = __expf(sacc[nt][r] - m[r]);
          sacc[nt][r] = p; ps += p;
        }
#pragma unroll
        for (int off = 8; off; off >>= 1) ps += __shfl_xor(ps, off);
        l[r] += ps;
      }
#pragma unroll
      for (int nt = 0; nt < 4; ++nt)
#pragma unroll
        for (int r = 0; r < 4; ++r)
          lP[w][(lg * 4 + r) * 72 + nt * 16 + lr] = f2bf(sacc[nt][r]);
      // V resident (own 4 oldest drained; barrier makes it collective); K may fly
      if (u + 1 < ntiles) { asm volatile("s_waitcnt vmcnt(4)" ::: "memory"); }
      else               { asm volatile("s_waitcnt vmcnt(0)" ::: "memory"); }
      __builtin_amdgcn_s_barrier();
      __builtin_amdgcn_sched_barrier(0);
      __builtin_amdgcn_s_setprio(1);
#pragma unroll
      for (int kc = 0; kc < 2; ++kc) {
        bf16x8 pf = *(const bf16x8*)&lP[w][lr * 72 + kc * 32 + lg * 8];
#pragma unroll
        for (int dt = 0; dt < 8; ++dt) {
          bf16x8 vf = *(const bf16x8*)&lV[(dt * 16 + lr) * 64 + (((kc * 4 + lg) ^ (lr & 7)) * 8)];
          o[dt] = __builtin_amdgcn_mfma_f32_16x16x32_bf16(pf, vf, o[dt], 0, 0, 0);
        }
      }
      __builtin_amdgcn_s_setprio(0);
      // drain K(u+1) (latency hidden under softmax+PV), then collective barrier:
      // next tile's QK may read any wave's staged K rows.
      asm volatile("s_waitcnt vmcnt(0)" ::: "memory");
      __builtin_amdgcn_s_barrier();
      __builtin_amdgcn_sched_barrier(0);
    }
#pragma unroll
    for (int r = 0; r < 4; ++r) {
      float inv = 1.f / l[r];
      int row = qb * 64 + (lg * 4 + r) * 4 + w;
      size_t ob = ((size_t)b * 512 + row) * 4096 + (size_t)h * 128;
#pragma unroll
      for (int dt = 0; dt < 8; ++dt)
        Out[ob + dt * 16 + lr] = o[dt][r] * inv;
    }
  }
}

extern "C" void kernel_launch(void* const* d_in, const int* in_sizes, int n_in,
                              void* d_out, int out_size, void* d_ws, size_t ws_size,
                              hipStream_t stream) {
  const float* X = (const float*)d_in[0];     // [4,512,4096]
  const float* W = (const float*)d_in[1];     // [4096,12288]
  const float* bias = (const float*)d_in[2];  // [12288]
  float* out = (float*)d_out;
  char* ws = (char*)d_ws;
  u16* Xb  = (u16*)(ws);
  u16* Wt  = (u16*)(ws + 16777216);
  u16* qkv = (u16*)(ws + 117440512);
  u16* Qb  = (u16*)(ws);
  u16* Kb  = (u16*)(ws + 16777216);
  u16* Vtb = (u16*)(ws + 33554432);

  k_castx<<<4096, 256, 0, stream>>>(X, Xb);
  k_wtrans<<<dim3(192, 64), 256, 0, stream>>>(W, Wt);
  k_gemm4<<<dim3(48, 16), 512, 0, stream>>>(Xb, Wt, bias, qkv);
  k_rope<<<1024, 256, 0, stream>>>(qkv, Qb, Kb, Vtb);
  k_attn3<<<512, 256, 0, stream>>>(Qb, Kb, Vtb, out);
}

// Round 7
// 283.853 us; speedup vs baseline: 1.5944x; 1.0885x over previous
//
#include <hip/hip_runtime.h>

typedef unsigned short u16;
typedef __attribute__((ext_vector_type(8))) __bf16 bf16x8;
typedef __attribute__((ext_vector_type(4))) float f32x4;
typedef __attribute__((ext_vector_type(4))) float f4;
typedef __attribute__((ext_vector_type(8))) unsigned short u16x8;
typedef __attribute__((ext_vector_type(4))) unsigned short u16x4;

__device__ __forceinline__ u16 f2bf(float f) {
  union { float f; unsigned int u; } x; x.f = f;
  unsigned int r = x.u + 0x7FFFu + ((x.u >> 16) & 1u);
  return (u16)(r >> 16);
}
__device__ __forceinline__ float bf2f(u16 h) {
  union { unsigned int u; float f; } x; x.u = ((unsigned int)h) << 16;
  return x.f;
}

typedef const __attribute__((address_space(1))) void* gas_t;
typedef __attribute__((address_space(3))) void* las_t;
__device__ __forceinline__ void gload_lds16(const void* g, void* l) {
  __builtin_amdgcn_global_load_lds((gas_t)g, (las_t)l, 16, 0, 0);
}

#define WAITL0 do { asm volatile("s_waitcnt lgkmcnt(0)" ::: "memory"); \
                    __builtin_amdgcn_sched_barrier(0); } while (0)

// ---------------- cast X fp32 -> bf16 ----------------
__global__ __launch_bounds__(256) void k_castx(const float* __restrict__ X, u16* __restrict__ Xb) {
  int i = blockIdx.x * 256 + threadIdx.x;          // 8 floats per thread
  const f4* src = (const f4*)X + (size_t)i * 2;
  f4 a = src[0], b = src[1];
  u16x8 o;
#pragma unroll
  for (int j = 0; j < 4; ++j) { o[j] = f2bf(a[j]); o[4 + j] = f2bf(b[j]); }
  *((u16x8*)Xb + i) = o;
}

// ---------------- transpose+cast W [4096][12288] fp32 -> Wt [12288][4096] bf16 ----
__global__ __launch_bounds__(256) void k_wtrans(const float* __restrict__ W, u16* __restrict__ Wt) {
  const int N = 12288, K = 4096;
  int n0 = blockIdx.x * 64;
  int k0 = blockIdx.y * 64;
  int t = threadIdx.x;
  __shared__ float tile[64][65];
  int tr = t >> 4;           // 0..15
  int tc4 = (t & 15) * 4;    // 0..60
#pragma unroll
  for (int p = 0; p < 4; ++p) {
    int k = k0 + p * 16 + tr;
    f4 v = *(const f4*)&W[(size_t)k * N + n0 + tc4];
#pragma unroll
    for (int j = 0; j < 4; ++j) tile[p * 16 + tr][tc4 + j] = v[j];
  }
  __syncthreads();
#pragma unroll
  for (int p = 0; p < 4; ++p) {
    int n = n0 + p * 16 + tr;
    u16x4 o;
#pragma unroll
    for (int j = 0; j < 4; ++j) o[j] = f2bf(tile[tc4 + j][p * 16 + tr]);
    *(u16x4*)&Wt[(size_t)n * K + k0 + tc4] = o;
  }
}

// ---------------- GEMM + fused bias/RoPE/layout epilogue ----------------
#define MFMA8(FA, FB, IB, JB)                                              \
  _Pragma("unroll")                                                        \
  for (int i2 = 0; i2 < 2; ++i2)                                           \
    _Pragma("unroll")                                                      \
    for (int j2 = 0; j2 < 2; ++j2)                                         \
      _Pragma("unroll")                                                    \
      for (int kk = 0; kk < 2; ++kk)                                       \
        acc[(IB) + i2][(JB) + j2] = __builtin_amdgcn_mfma_f32_16x16x32_bf16( \
            FA[i2][kk], FB[j2][kk], acc[(IB) + i2][(JB) + j2], 0, 0, 0);

// SA = slab of tile U; SB = slab of tile U+1; SC = slab written for tile U+2.
#define TILE_BODY(U, SA, SB, SC, STAGE, VMN, CROSS)                         \
  {                                                                         \
    const size_t kc_ = (size_t)((U) + 2) * 64;                              \
    /* ---- P0: A0xB0 (both prefetched last tile) ---- */                   \
    WAITL0;                                                                 \
    _Pragma("unroll") for (int j2 = 0; j2 < 2; ++j2)                        \
      _Pragma("unroll") for (int kk = 0; kk < 2; ++kk)                      \
        fB1[j2][kk] = *(const bf16x8*)&lds[(SA) * 24576 + bBase + (2 + j2) * 1024 + ch[kk]]; \
    __builtin_amdgcn_sched_barrier(0);                                      \
    __builtin_amdgcn_s_setprio(1); MFMA8(fA0, fB0, 0, 0);                   \
    __builtin_amdgcn_s_setprio(0);                                          \
    _Pragma("unroll") for (int i2 = 0; i2 < 2; ++i2)                        \
      _Pragma("unroll") for (int kk = 0; kk < 2; ++kk)                      \
        fA1[i2][kk] = *(const bf16x8*)&lds[(SA) * 24576 + aBase + (2 + i2) * 1024 + ch[kk]]; \
    if (STAGE) {                                                            \
      gload_lds16(aS + kc_,         &lds[(SC) * 24576 + (w * 16) * 64]);    \
      gload_lds16(aS + 8 * K + kc_, &lds[(SC) * 24576 + (w * 16 + 8) * 64]);\
    }                                                                       \
    /* ---- P1: A0xB1 (B1 drained, A1 may fly; DS in-order) ---- */         \
    asm volatile("s_waitcnt lgkmcnt(4)" ::: "memory");                      \
    __builtin_amdgcn_sched_barrier(0);                                      \
    __builtin_amdgcn_s_setprio(1); MFMA8(fA0, fB1, 0, 2);                   \
    __builtin_amdgcn_s_setprio(0);                                          \
    if (STAGE) {                                                            \
      gload_lds16(bS + kc_,         &lds[(SC) * 24576 + 8192 + (w * 32) * 64]); \
      gload_lds16(bS + 8 * K + kc_, &lds[(SC) * 24576 + 8192 + (w * 32 + 8) * 64]); \
    }                                                                       \
    /* ---- P2: A1xB0 ---- */                                               \
    WAITL0;                                                                 \
    __builtin_amdgcn_s_setprio(1); MFMA8(fA1, fB0, 2, 0);                   \
    __builtin_amdgcn_s_setprio(0);                                          \
    if (STAGE) {                                                            \
      gload_lds16(bS + 16 * K + kc_, &lds[(SC) * 24576 + 8192 + (w * 32 + 16) * 64]); \
      gload_lds16(bS + 24 * K + kc_, &lds[(SC) * 24576 + 8192 + (w * 32 + 24) * 64]); \
    }                                                                       \
    if ((VMN) == 6)      { asm volatile("s_waitcnt vmcnt(6)" ::: "memory"); } \
    else if ((VMN) == 0) { asm volatile("s_waitcnt vmcnt(0)" ::: "memory"); } \
    if (CROSS) {                                                            \
      __builtin_amdgcn_s_barrier();                                         \
      __builtin_amdgcn_sched_barrier(0);                                    \
      _Pragma("unroll") for (int i2 = 0; i2 < 2; ++i2)                      \
        _Pragma("unroll") for (int kk = 0; kk < 2; ++kk) {                  \
          fA0[i2][kk] = *(const bf16x8*)&lds[(SB) * 24576 + aBase + i2 * 1024 + ch[kk]]; \
          fB0[i2][kk] = *(const bf16x8*)&lds[(SB) * 24576 + bBase + i2 * 1024 + ch[kk]]; \
        }                                                                   \
      __builtin_amdgcn_sched_barrier(0);                                    \
    }                                                                       \
    /* ---- P3: A1xB1 (all operands resident; prefetch hides here) ---- */  \
    __builtin_amdgcn_s_setprio(1); MFMA8(fA1, fB1, 2, 2);                   \
    __builtin_amdgcn_s_setprio(0);                                          \
  }

__global__ __launch_bounds__(512) void k_gemm5(const u16* __restrict__ A, const u16* __restrict__ Bt,
                                               const float* __restrict__ bias,
                                               u16* __restrict__ Qo, u16* __restrict__ Ko,
                                               u16* __restrict__ Vto) {
  const int K = 4096;
  const int bn = blockIdx.x, bm = blockIdx.y;    // 48 x 16, bn-fast rasterization
  const int t = threadIdx.x, w = t >> 6, lane = t & 63;
  const int lr = lane & 15, lg = lane >> 4;
  const int wm = w >> 2, wn = w & 3;
  __shared__ u16 lds[3 * 24576];                 // K-loop slabs; reused as epilogue staging

  f32x4 acc[4][4] = {};
  bf16x8 fA0[2][2], fA1[2][2], fB0[2][2], fB1[2][2];   // [sub][kk]

  const int r8 = lane >> 3;
  const int cgs = (lane & 7) ^ r8;
  const u16* aS = A  + (size_t)(bm * 128 + w * 16 + r8) * K + cgs * 8;
  const u16* bS = Bt + (size_t)(bn * 256 + w * 32 + r8) * K + cgs * 8;

  const int aBase = (wm * 64 + lr) * 64;
  const int bBase = 8192 + (wn * 64 + lr) * 64;
  const int ch[2] = { ((lg ^ (lr & 7)) * 8), (((4 + lg) ^ (lr & 7)) * 8) };

#pragma unroll
  for (int tt = 0; tt < 2; ++tt) {
    gload_lds16(aS + tt * 64,         &lds[tt * 24576 + (w * 16) * 64]);
    gload_lds16(aS + 8 * K + tt * 64, &lds[tt * 24576 + (w * 16 + 8) * 64]);
#pragma unroll
    for (int p = 0; p < 4; ++p)
      gload_lds16(bS + p * 8 * K + tt * 64, &lds[tt * 24576 + 8192 + (w * 32 + p * 8) * 64]);
  }
  asm volatile("s_waitcnt vmcnt(6)" ::: "memory");
  __builtin_amdgcn_s_barrier();
#pragma unroll
  for (int i2 = 0; i2 < 2; ++i2)
#pragma unroll
    for (int kk = 0; kk < 2; ++kk) {
      fA0[i2][kk] = *(const bf16x8*)&lds[aBase + i2 * 1024 + ch[kk]];
      fB0[i2][kk] = *(const bf16x8*)&lds[bBase + i2 * 1024 + ch[kk]];
    }

  for (int v = 0; v < 20; ++v) {
    TILE_BODY(3 * v,     0, 1, 2, true, 6, true)
    TILE_BODY(3 * v + 1, 1, 2, 0, true, 6, true)
    TILE_BODY(3 * v + 2, 2, 0, 1, true, 6, true)
  }
  TILE_BODY(60, 0, 1, 2, true,  6, true)
  TILE_BODY(61, 1, 2, 0, true,  6, true)
  TILE_BODY(62, 2, 0, 1, false, 0, true)
  TILE_BODY(63, 0, 1, 2, false, -1, false)

  // ===== Epilogue E1: stage acc+bias as bf16 into LDS [128 rows][2 halves x 136] =====
  // chunk-swizzle: storage chunk = (cl>>3) ^ (row&7); elem = chunk*8 + (cl&7).
  __syncthreads();   // all waves done reading K-loop slabs
#pragma unroll
  for (int i = 0; i < 4; ++i) {
    int rbase = wm * 64 + i * 16 + lg * 4;
#pragma unroll
    for (int j = 0; j < 4; ++j) {
      int c = wn * 64 + j * 16 + lr;
      int H = c >> 7, cl = c & 127;
      float bv = bias[bn * 256 + c];
#pragma unroll
      for (int r = 0; r < 4; ++r) {
        int row = rbase + r;
        lds[row * 272 + H * 136 + (((cl >> 3) ^ (row & 7)) * 8) + (cl & 7)] =
            f2bf(acc[i][j][r] + bv);
      }
    }
  }
  __syncthreads();

  // ===== Epilogue E2: per-half output (q: rope+scale, k: rope, v: transpose) =====
  {
    const int H = w >> 2;                 // waves 0-3 -> half 0, 4-7 -> half 1
    const int cc = bn * 2 + H;
    const int type = cc % 3;              // 0=q, 1=k, 2=v
    const int h = cc / 3;
    const size_t bh = (size_t)(bm >> 2) * 32 + h;
    if (type < 2) {
      u16* dst = (type == 0) ? Qo : Ko;
      const float qs = (type == 0) ? 0.08838834765f : 1.0f;
      const int dc = lane & 15;           // d-chunk (8 d each)
      const int rsub = lane >> 4;
      const float sgn = (dc < 8) ? -1.f : 1.f;
      float ifr[8];
#pragma unroll
      for (int e = 0; e < 8; ++e) {
        int ii = (dc * 8 + e) & 63;
        ifr[e] = __expf((float)ii * -0.14391156831f);   // 10000^(-i/64)
      }
#pragma unroll
      for (int rr = 0; rr < 8; ++rr) {
        int row = (w & 3) * 32 + rr * 4 + rsub;
        int s_tok = (bm & 3) * 128 + row;
        int base = row * 272 + H * 136;
        u16x8 xv = *(u16x8*)&lds[base + ((dc ^ (row & 7)) * 8)];
        u16x8 yv = *(u16x8*)&lds[base + (((dc ^ 8) ^ (row & 7)) * 8)];
        u16x8 ov;
#pragma unroll
        for (int e = 0; e < 8; ++e) {
          float sv, cv; __sincosf((float)s_tok * ifr[e], &sv, &cv);
          ov[e] = f2bf((bf2f(xv[e]) * cv + sgn * bf2f(yv[e]) * sv) * qs);
        }
        *(u16x8*)&dst[(bh * 512 + s_tok) * 128 + dc * 8] = ov;
      }
    } else {
      // v: Vt[bh][d][s]; rotated row order de-correlates banks
      const int sc = lane & 7;            // s-chunk of 16
      const int dd = lane >> 3;           // 0..7
#pragma unroll
      for (int pass = 0; pass < 4; ++pass) {
        int d = (w & 3) * 32 + pass * 8 + dd;
        u16x8 o0, o1;
#pragma unroll
        for (int i = 0; i < 8; ++i) {
          int off = (i + sc) & 7;
          int row = sc * 16 + off;
          int chunk = (d >> 3) ^ off;     // row&7 == off
          o0[off] = lds[row * 272 + H * 136 + chunk * 8 + (d & 7)];
          o1[off] = lds[(row + 8) * 272 + H * 136 + chunk * 8 + (d & 7)];
        }
        size_t vb = (bh * 128 + d) * 512 + (size_t)(bm & 3) * 128 + sc * 16;
        *(u16x8*)&Vto[vb] = o0;
        *(u16x8*)&Vto[vb + 8] = o1;
      }
    }
  }
}

// ---------------- causal flash attention v4 ----------------
// Pair-balanced blocks (9 tile-units each); K AND V double-buffered; both
// next-tile stages issue at tile start; ONE vmcnt(0)+barrier per tile.
__global__ __launch_bounds__(256) void k_attn4(const u16* __restrict__ Q, const u16* __restrict__ Kg,
                                               const u16* __restrict__ Vt, float* __restrict__ Out) {
  int bid = blockIdx.x;            // 512
  int pair = bid & 3, bh = bid >> 2;
  int t = threadIdx.x, w = t >> 6, lane = t & 63;
  int lr = lane & 15, lg = lane >> 4;
  int b = bh >> 5, h = bh & 31;
  const u16* Kp = Kg + (size_t)bh * 512 * 128;
  const u16* Vp = Vt + (size_t)bh * 128 * 512;
  __shared__ u16 lK[2][8192];     // [64][128] swizzled (chunk16 ^= row&7)
  __shared__ u16 lV[2][8192];     // [128][64] swizzled (chunk8  ^= row&7)
  __shared__ u16 lP[4][16 * 72];  // per-wave, padded

  for (int half = 0; half < 2; ++half) {
    const int qb = half ? (7 - pair) : pair;
    const int ntiles = qb + 1;
    const u16* Qp = Q + ((size_t)bh * 512 + qb * 64) * 128;

    bf16x8 qf[4];
#pragma unroll
    for (int dc = 0; dc < 4; ++dc)
      qf[dc] = *(const bf16x8*)(Qp + (size_t)(lr * 4 + w) * 128 + dc * 32 + lg * 8);

    f32x4 o[8] = {};
    float m[4], l[4];
#pragma unroll
    for (int r = 0; r < 4; ++r) { m[r] = -1e30f; l[r] = 0.f; }

    // prologue: stage V(0), K(0) into buf 0 (prev half's readers drained at its last barrier)
#pragma unroll
    for (int p = 0; p < 4; ++p) {
      int rowv = w * 32 + p * 8 + (lane >> 3);
      int cv = (lane & 7) ^ ((lane >> 3) & 7);
      gload_lds16(Vp + (size_t)rowv * 512 + cv * 8, &lV[0][(w * 32 + p * 8) * 64]);
      int rowk = w * 16 + p * 4 + (lane >> 4);
      int ck = (lane & 15) ^ (rowk & 7);
      gload_lds16(Kp + (size_t)rowk * 128 + ck * 8, &lK[0][(w * 16 + p * 4) * 128]);
    }
    asm volatile("s_waitcnt vmcnt(0)" ::: "memory");
    __builtin_amdgcn_s_barrier();
    __builtin_amdgcn_sched_barrier(0);

    for (int u = 0; u < ntiles; ++u) {
      const int kv0 = u * 64;
      const int kb = u & 1;
      // issue next tile's V and K into buf^1 (drained at end-of-tile vmcnt)
      if (u + 1 < ntiles) {
#pragma unroll
        for (int p = 0; p < 4; ++p) {
          int rowv = w * 32 + p * 8 + (lane >> 3);
          int cv = (lane & 7) ^ ((lane >> 3) & 7);
          gload_lds16(Vp + (size_t)rowv * 512 + kv0 + 64 + cv * 8, &lV[kb ^ 1][(w * 32 + p * 8) * 64]);
          int rowk = w * 16 + p * 4 + (lane >> 4);
          int ck = (lane & 15) ^ (rowk & 7);
          gload_lds16(Kp + (size_t)(kv0 + 64 + rowk) * 128 + ck * 8, &lK[kb ^ 1][(w * 16 + p * 4) * 128]);
        }
      }
      f32x4 sacc[4] = {};
      __builtin_amdgcn_s_setprio(1);
#pragma unroll
      for (int nt = 0; nt < 4; ++nt)
#pragma unroll
        for (int dc = 0; dc < 4; ++dc) {
          bf16x8 kf = *(const bf16x8*)&lK[kb][(nt * 16 + lr) * 128 + (((dc * 4 + lg) ^ (lr & 7)) * 8)];
          sacc[nt] = __builtin_amdgcn_mfma_f32_16x16x32_bf16(qf[dc], kf, sacc[nt], 0, 0, 0);
        }
      __builtin_amdgcn_s_setprio(0);
      if (u == ntiles - 1) {
#pragma unroll
        for (int nt = 0; nt < 4; ++nt)
#pragma unroll
          for (int r = 0; r < 4; ++r)
            if (kv0 + nt * 16 + lr > qb * 64 + (lg * 4 + r) * 4 + w) sacc[nt][r] = -1e30f;
      }
      float mx[4];
#pragma unroll
      for (int r = 0; r < 4; ++r) {
        float v = fmaxf(fmaxf(sacc[0][r], sacc[1][r]), fmaxf(sacc[2][r], sacc[3][r]));
#pragma unroll
        for (int off = 8; off; off >>= 1) v = fmaxf(v, __shfl_xor(v, off));
        mx[r] = v;
      }
      int needs = (mx[0] > m[0] + 8.f) | (mx[1] > m[1] + 8.f) |
                  (mx[2] > m[2] + 8.f) | (mx[3] > m[3] + 8.f);
      if (__any(needs)) {
#pragma unroll
        for (int r = 0; r < 4; ++r) {
          float mn = fmaxf(m[r], mx[r]);
          float a = __expf(m[r] - mn);
          m[r] = mn; l[r] *= a;
#pragma unroll
          for (int dt = 0; dt < 8; ++dt) o[dt][r] *= a;
        }
      }
#pragma unroll
      for (int r = 0; r < 4; ++r) {
        float ps = 0.f;
#pragma unroll
        for (int nt = 0; nt < 4; ++nt) {
          float p = __expf(sacc[nt][r] - m[r]);
          sacc[nt][r] = p; ps += p;
        }
#pragma unroll
        for (int off = 8; off; off >>= 1) ps += __shfl_xor(ps, off);
        l[r] += ps;
      }
#pragma unroll
      for (int nt = 0; nt < 4; ++nt)
#pragma unroll
        for (int r = 0; r < 4; ++r)
          lP[w][(lg * 4 + r) * 72 + nt * 16 + lr] = f2bf(sacc[nt][r]);
      // PV from resident buf (lP per-wave; compiler inserts lgkm waits)
      __builtin_amdgcn_s_setprio(1);
#pragma unroll
      for (int kc = 0; kc < 2; ++kc) {
        bf16x8 pf = *(const bf16x8*)&lP[w][lr * 72 + kc * 32 + lg * 8];
#pragma unroll
        for (int dt = 0; dt < 8; ++dt) {
          bf16x8 vf = *(const bf16x8*)&lV[kb][(dt * 16 + lr) * 64 + (((kc * 4 + lg) ^ (lr & 7)) * 8)];
          o[dt] = __builtin_amdgcn_mfma_f32_16x16x32_bf16(pf, vf, o[dt], 0, 0, 0);
        }
      }
      __builtin_amdgcn_s_setprio(0);
      // single drain+barrier: next tile staged collectively; this tile's LDS reads done
      asm volatile("s_waitcnt vmcnt(0)" ::: "memory");
      __builtin_amdgcn_s_barrier();
      __builtin_amdgcn_sched_barrier(0);
    }
#pragma unroll
    for (int r = 0; r < 4; ++r) {
      float inv = 1.f / l[r];
      int row = qb * 64 + (lg * 4 + r) * 4 + w;
      size_t ob = ((size_t)b * 512 + row) * 4096 + (size_t)h * 128;
#pragma unroll
      for (int dt = 0; dt < 8; ++dt)
        Out[ob + dt * 16 + lr] = o[dt][r] * inv;
    }
  }
}

extern "C" void kernel_launch(void* const* d_in, const int* in_sizes, int n_in,
                              void* d_out, int out_size, void* d_ws, size_t ws_size,
                              hipStream_t stream) {
  const float* X = (const float*)d_in[0];     // [4,512,4096]
  const float* W = (const float*)d_in[1];     // [4096,12288]
  const float* bias = (const float*)d_in[2];  // [12288]
  float* out = (float*)d_out;
  char* ws = (char*)d_ws;
  u16* Xb  = (u16*)(ws);
  u16* Wt  = (u16*)(ws + 16777216);
  u16* Qb  = (u16*)(ws + 117440512);
  u16* Kb  = (u16*)(ws + 134217728);
  u16* Vtb = (u16*)(ws + 150994944);

  k_castx<<<4096, 256, 0, stream>>>(X, Xb);
  k_wtrans<<<dim3(192, 64), 256, 0, stream>>>(W, Wt);
  k_gemm5<<<dim3(48, 16), 512, 0, stream>>>(Xb, Wt, bias, Qb, Kb, Vtb);
  k_attn4<<<512, 256, 0, stream>>>(Qb, Kb, Vtb, out);
}